// Round 11
// baseline (121.359 us; speedup 1.0000x reference)
//
#include <hip/hip_runtime.h>

// ---------- types ----------
typedef __attribute__((ext_vector_type(8))) __bf16 bf16x8;
typedef __attribute__((ext_vector_type(4))) float f32x4;
typedef __attribute__((ext_vector_type(16))) float f32x16;
typedef __attribute__((ext_vector_type(4))) unsigned short us4;
typedef __attribute__((ext_vector_type(4))) unsigned int u32x4;
typedef __attribute__((address_space(3))) void* as3vp;
typedef const __attribute__((address_space(1))) void* as1vp;

#define GLOAD_LDS16(g, l) __builtin_amdgcn_global_load_lds((as1vp)(g), (as3vp)(l), 16, 0, 0)

#if __has_builtin(__builtin_amdgcn_exp2f)
#define EXP2(x) __builtin_amdgcn_exp2f(x)
#else
#define EXP2(x) __expf((x) * 0.6931471805599453f)
#endif

__device__ __forceinline__ unsigned short f2bf(float f) {
  unsigned u = __builtin_bit_cast(unsigned, f);
  u += 0x7FFFu + ((u >> 16) & 1u);   // RNE
  return (unsigned short)(u >> 16);
}
__device__ __forceinline__ float bf2f(unsigned short u) {
  return __builtin_bit_cast(float, (unsigned)u << 16);
}
__device__ __forceinline__ unsigned int pkbf(float a, float b) {
  unsigned int r;
  asm("v_cvt_pk_bf16_f32 %0, %1, %2" : "=v"(r) : "v"(a), "v"(b));
  return r;
}

// ---------- pre_q f32 -> bf16, fused with out-tail passthrough ----------
__global__ void cvt_pq_tail(const float* __restrict__ x, unsigned short* __restrict__ y,
                            float* __restrict__ out) {
  const int i = blockIdx.x * 256 + threadIdx.x;
  if (i >= 1310720) return;
  float4 v = ((const float4*)x)[i];
  us4 o;
  o.x = f2bf(v.x); o.y = f2bf(v.y); o.z = f2bf(v.z); o.w = f2bf(v.w);
  ((us4*)y)[i] = o;
  if ((i % 320) >= 256) ((float4*)out)[i] = v;
}

// ---------- pre_value_key f32 -> bf16 ----------
__global__ void cvt_f32_bf16(const float* __restrict__ x, unsigned short* __restrict__ y, int n4) {
  int i = blockIdx.x * 256 + threadIdx.x;
  if (i >= n4) return;
  float4 v = ((const float4*)x)[i];
  us4 o;
  o.x = f2bf(v.x); o.y = f2bf(v.y); o.z = f2bf(v.z); o.w = f2bf(v.w);
  ((us4*)y)[i] = o;
}

// ---------- merged W (KxN f32) -> WT (NxK bf16), z selects Wq/Wk/Wv ----------
__global__ void transpose_w3(const float* __restrict__ Wq, const float* __restrict__ Wk,
                             const float* __restrict__ Wv,
                             unsigned short* __restrict__ WqT, unsigned short* __restrict__ WkT,
                             unsigned short* __restrict__ WvT) {
  const int z = blockIdx.z;
  const int K = (z == 0) ? 1280 : 1024;
  if ((int)blockIdx.y * 32 >= K) return;
  const float* W = (z == 0) ? Wq : ((z == 1) ? Wk : Wv);
  unsigned short* WT = (z == 0) ? WqT : ((z == 1) ? WkT : WvT);
  __shared__ float t[32][33];
  const int tx = threadIdx.x & 31, ty = threadIdx.x >> 5;
  const int n0 = blockIdx.x * 32, k0 = blockIdx.y * 32;
#pragma unroll
  for (int i = 0; i < 32; i += 8)
    t[ty + i][tx] = W[(size_t)(k0 + ty + i) * 1024 + n0 + tx];
  __syncthreads();
#pragma unroll
  for (int i = 0; i < 32; i += 8)
    WT[(size_t)(n0 + ty + i) * K + k0 + tx] = f2bf(t[tx][ty + i]);
}

// ---------- km reduce (atomic, 256 blocks) + addm (f32) production ----------
__global__ void km_reduce(const unsigned short* __restrict__ Kbb, const float* __restrict__ mask,
                          float* __restrict__ km, float* __restrict__ addm) {
  if (blockIdx.x < 16) {
    const int i = blockIdx.x * 256 + threadIdx.x;   // 0..4095
    addm[i] = (mask[i] != 0.f) ? 0.f : -1e30f;
  }
  __shared__ float red[16][64];
  const int bh = blockIdx.x >> 3, chunk = blockIdx.x & 7;
  const int b = bh >> 4;
  const int dg = (threadIdx.x & 15) * 4, rg = threadIdx.x >> 4;
  const unsigned short* kb = Kbb + (size_t)(b * 2048) * 1024 + (bh & 15) * 64 + dg;
  const float* mr = mask + b * 2048;
  float a0 = 0.f, a1 = 0.f, a2 = 0.f, a3 = 0.f;
  const int kv0 = chunk * 256;
#pragma unroll 4
  for (int kv = kv0 + rg; kv < kv0 + 256; kv += 16) {
    const float mv = mr[kv];
    us4 kq = *(const us4*)(kb + (size_t)kv * 1024);
    a0 = fmaf(mv, bf2f(kq.x), a0); a1 = fmaf(mv, bf2f(kq.y), a1);
    a2 = fmaf(mv, bf2f(kq.z), a2); a3 = fmaf(mv, bf2f(kq.w), a3);
  }
  red[rg][dg] = a0; red[rg][dg + 1] = a1; red[rg][dg + 2] = a2; red[rg][dg + 3] = a3;
  __syncthreads();
  if (threadIdx.x < 64) {
    float s = 0.f;
#pragma unroll
    for (int i = 0; i < 16; ++i) s += red[i][threadIdx.x];
    atomicAdd(&km[bh * 64 + threadIdx.x], s);
  }
}

// ---------- merged Q/K/V GEMM, 128x128 tile, dbuf single-barrier ----------
// z=0: Q row-major (scaled 0.125*log2e). z=1: K row-major.
// z=2: V -> LDS transpose -> fragment-ordered VF stores (dense 256B runs).
__global__ __launch_bounds__(256, 2)
void gemm_all(const unsigned short* __restrict__ Aq,
              const unsigned short* __restrict__ Akv,
              const unsigned short* __restrict__ WqT,
              const unsigned short* __restrict__ WkT,
              const unsigned short* __restrict__ WvT,
              const float* __restrict__ bq,
              const float* __restrict__ bk,
              const float* __restrict__ bv,
              unsigned short* __restrict__ Qout,
              unsigned short* __restrict__ Kout,
              unsigned short* __restrict__ VFout) {
  __shared__ unsigned short sA[2][128 * 64];
  __shared__ unsigned short sB[2][128 * 64];
  const int z = blockIdx.z;
  const int KDIM = (z == 0) ? 1280 : 1024;
  const unsigned short* A = (z == 0) ? Aq : Akv;
  const unsigned short* Bt = (z == 0) ? WqT : ((z == 1) ? WkT : WvT);

  const int tid = threadIdx.x, lane = tid & 63, w = tid >> 6;
  const int l15 = lane & 15, lhi = lane >> 4;
  const int wm = w >> 1, wn = w & 1;
  const int row0 = blockIdx.x * 128, col0 = blockIdx.y * 128;

  const f32x4 zv = {0.f, 0.f, 0.f, 0.f};
  f32x4 acc[4][4];
#pragma unroll
  for (int m = 0; m < 4; ++m)
#pragma unroll
    for (int n = 0; n < 4; ++n) acc[m][n] = zv;

  auto stage = [&](int buf, int kt) {
#pragma unroll
    for (int i = 0; i < 4; ++i) {
      const int c = i * 256 + tid;                     // 0..1023
      const int r = c >> 3, kc = ((c & 7) ^ (r & 7)) * 8;
      GLOAD_LDS16(A + (size_t)(row0 + r) * KDIM + kt + kc, &sA[buf][0] + c * 8);
      GLOAD_LDS16(Bt + (size_t)(col0 + r) * KDIM + kt + kc, &sB[buf][0] + c * 8);
    }
  };

  const int NT = KDIM / 64;
  stage(0, 0);
  __syncthreads();
  int cur = 0;
  for (int t = 0; t < NT; ++t) {
    if (t + 1 < NT) stage(cur ^ 1, (t + 1) * 64);
    const unsigned short* sAb = &sA[cur][0];
    const unsigned short* sBb = &sB[cur][0];
#pragma unroll
    for (int ks = 0; ks < 2; ++ks) {
      const int koS = (ks * 32 + lhi * 8) ^ ((l15 & 7) * 8);
      bf16x8 af[4], bfr[4];
#pragma unroll
      for (int m = 0; m < 4; ++m) af[m] = *(const bf16x8*)(sAb + (wm * 64 + m * 16 + l15) * 64 + koS);
#pragma unroll
      for (int n = 0; n < 4; ++n) bfr[n] = *(const bf16x8*)(sBb + (wn * 64 + n * 16 + l15) * 64 + koS);
#pragma unroll
      for (int m = 0; m < 4; ++m)
#pragma unroll
        for (int n = 0; n < 4; ++n)
          acc[m][n] = __builtin_amdgcn_mfma_f32_16x16x32_bf16(af[m], bfr[n], acc[m][n], 0, 0, 0);
    }
    __syncthreads();
    cur ^= 1;
  }

  if (z <= 1) {
    unsigned short* C = (z == 0) ? Qout : Kout;
    const float* bias = (z == 0) ? bq : bk;
    const float scale = (z == 0) ? 0.18033688f : 1.0f;   // 0.125 * log2(e)
#pragma unroll
    for (int n = 0; n < 4; ++n) {
      const int gc = col0 + wn * 64 + n * 16 + l15;
      const float bb = bias[gc];
#pragma unroll
      for (int m = 0; m < 4; ++m) {
        const int gr0 = row0 + wm * 64 + m * 16 + lhi * 4;
#pragma unroll
        for (int r = 0; r < 4; ++r)
          C[(size_t)(gr0 + r) * 1024 + gc] = f2bf((acc[m][n][r] + bb) * scale);
      }
    }
  } else {
    // V: transpose 128(kv) x 128(ch) tile through LDS, then fragment-ordered stores.
    __syncthreads();
    unsigned* tb = (unsigned*)&sA[0][0];   // 128 rows x 64 u32
#pragma unroll
    for (int n = 0; n < 4; ++n) {
      const int gcL = wn * 64 + n * 16 + l15;          // local ch 0..127
      const float bb = bv[col0 + gcL];
#pragma unroll
      for (int m = 0; m < 4; ++m) {
#pragma unroll
        for (int k = 0; k < 2; ++k) {
          const int grPair = wm * 32 + m * 8 + lhi * 2 + k;   // kv pair 0..63
          const int W = (grPair & 3) | ((((grPair >> 2) ^ gcL) & 15) << 2);
          tb[gcL * 64 + W] = pkbf(acc[m][n][2 * k] + bb, acc[m][n][2 * k + 1] + bb);
        }
      }
    }
    __syncthreads();
    const int b_ = row0 >> 11;
#pragma unroll
    for (int it = 0; it < 8; ++it) {
      const int c = it * 256 + tid;                    // 0..2047
      const int gcL = (c & 63) + ((c >> 10) << 6);     // d-inner for dense frag stores
      const int u = (c >> 6) & 15;                     // kv-8-group
      const int W4 = (u ^ gcL) & 15;
      u32x4 o = *(const u32x4*)(tb + gcL * 64 + W4 * 4);
      const int kv0 = (row0 & 2047) + u * 8;
      const int ch = col0 + gcL;
      const int hh2 = ch >> 6, d = ch & 63;
      const int t2 = kv0 >> 6, ks2 = (kv0 >> 4) & 3, h5v = (kv0 >> 3) & 1;
      const size_t off = ((size_t)(b_ * 16 + hh2) << 17) +
                         (size_t)(((t2 * 4 + ks2) * 2 + (d >> 5)) * 64 + h5v * 32 + (d & 31)) * 8;
      *(u32x4*)(VFout + off) = o;
    }
  }
}

// ---------- fused flash attention + pooled gate + blend ----------
// 512 blocks (XCD-swizzled bh), 256 threads = 4 waves, 32 q-rows/wave.
// 128-row KV SUPER-TILES: two 64-tiles per barrier phase, single softmax
// state. Halves barrier/max-tree/rescale counts; 16 QK MFMAs issue as 4
// interleaved chains; V (frag-ordered, reg-direct) in flight under QK+SM.
__global__ __launch_bounds__(256, 2)
void attn_fused(const unsigned short* __restrict__ Q,    // (B*SQ,1024) bf16, 0.125*log2e scaled
                const unsigned short* __restrict__ Kb,   // (B*SV,1024) bf16 row-major
                const unsigned short* __restrict__ VF,   // frag-ordered V^T
                const float* __restrict__ addm_g,        // (B,SV) 0/-1e30
                const float* __restrict__ km,            // (B,H,64)
                const float* __restrict__ counts,        // (B)
                const float* __restrict__ gain,          // (H)
                const float* __restrict__ gbias,         // (H)
                const float* __restrict__ pq,            // (B*SQ,1280) f32
                float* __restrict__ out) {               // (B*SQ,1280) f32
  __shared__ __align__(16) char smem[40960];
  unsigned short* sK = (unsigned short*)smem;            // [2][128*64] 32 KB
  float* saddm = (float*)(smem + 32768);                 // [2048] 8 KB
  float* sOT = (float*)smem;                             // epilogue overlay (32 KB)

  const int tid = threadIdx.x, lane = tid & 63, w = tid >> 6;
  const int l31 = lane & 31, h5 = lane >> 5;
  const int f = blockIdx.x;
  const int qt = (f >> 3) & 15;
  const int bh = (f & 7) + 8 * (f >> 7);
  const int b = bh >> 4, hh = bh & 15;
  const int q0 = qt * 128;

  // stage additive mask (2048 f32)
  GLOAD_LDS16(addm_g + b * 2048 + tid * 4, (char*)saddm + tid * 16);
  GLOAD_LDS16(addm_g + b * 2048 + 1024 + tid * 4, (char*)saddm + 4096 + tid * 16);

  // Q fragments (B-operand): lane l31 = q col, k = ks*16 + h5*8 + j
  bf16x8 qf[4];
  {
    const unsigned short* qp = Q + (size_t)(b * 2048 + q0 + w * 32 + l31) * 1024 + hh * 64 + h5 * 8;
#pragma unroll
    for (int ks = 0; ks < 4; ++ks) qf[ks] = *(const bf16x8*)(qp + ks * 16);
  }

  // pooled = km . q (log2-scaled; corrected by ln2 in the gate)
  float pl_s = 0.f;
  {
    const float* kmp = km + (b * 16 + hh) * 64 + h5 * 8;
#pragma unroll
    for (int ks = 0; ks < 4; ++ks) {
      f32x4 ka = *(const f32x4*)(kmp + ks * 16);
      f32x4 kb4 = *(const f32x4*)(kmp + ks * 16 + 4);
#pragma unroll
      for (int j = 0; j < 4; ++j)
        pl_s += (float)qf[ks][j] * ka[j] + (float)qf[ks][j + 4] * kb4[j];
    }
    float ta = pl_s, tb = pl_s;
    asm("v_permlane32_swap_b32 %0, %1" : "+v"(ta), "+v"(tb));
    pl_s = ta + tb;
  }

  const unsigned short* Kbase = Kb + (size_t)(b * 2048) * 1024 + hh * 64;
  const unsigned short* VFb = VF + ((size_t)bh << 17) + lane * 8;

  f32x16 o0, o1, l_vec;
#pragma unroll
  for (int r = 0; r < 16; ++r) { o0[r] = 0.f; o1[r] = 0.f; l_vec[r] = 0.f; }
  float m_ = -1e30f;

  // stage 128 kv rows (two 64-tiles) per phase
  auto stageK = [&](int buf, int kv) {
#pragma unroll
    for (int i = 0; i < 4; ++i) {
      const int c = i * 256 + tid;                       // 0..1023
      const int r = c >> 3, sl = (c & 7) ^ (r & 7);
      GLOAD_LDS16(Kbase + (size_t)(kv + r) * 1024 + sl * 8, (char*)sK + buf * 16384 + c * 16);
    }
  };

  auto ldV = [&](int t, bf16x8 (&vv)[8]) {
    const unsigned short* p = VFb + (size_t)t * 4096;
#pragma unroll
    for (int i = 0; i < 8; ++i) vv[i] = *(const bf16x8*)(p + i * 512);
  };

  // builds 4 PV B-fragments from two S/P vectors (in-register T12)
  auto mkpfs = [&](const f32x16& p0, const f32x16& p1, bf16x8 (&pfs)[4]) {
    unsigned x0 = pkbf(p0[0], p0[1]), y0 = pkbf(p0[2], p0[3]);
    unsigned z0 = pkbf(p0[4], p0[5]), w0 = pkbf(p0[6], p0[7]);
    asm("v_permlane32_swap_b32 %0, %1" : "+v"(x0), "+v"(z0));
    asm("v_permlane32_swap_b32 %0, %1" : "+v"(y0), "+v"(w0));
    u32x4 f0 = {x0, y0, z0, w0};
    pfs[0] = __builtin_bit_cast(bf16x8, f0);
    unsigned x1 = pkbf(p0[8], p0[9]), y1 = pkbf(p0[10], p0[11]);
    unsigned z1 = pkbf(p0[12], p0[13]), w1 = pkbf(p0[14], p0[15]);
    asm("v_permlane32_swap_b32 %0, %1" : "+v"(x1), "+v"(z1));
    asm("v_permlane32_swap_b32 %0, %1" : "+v"(y1), "+v"(w1));
    u32x4 f1 = {x1, y1, z1, w1};
    pfs[1] = __builtin_bit_cast(bf16x8, f1);
    unsigned x2 = pkbf(p1[0], p1[1]), y2 = pkbf(p1[2], p1[3]);
    unsigned z2 = pkbf(p1[4], p1[5]), w2 = pkbf(p1[6], p1[7]);
    asm("v_permlane32_swap_b32 %0, %1" : "+v"(x2), "+v"(z2));
    asm("v_permlane32_swap_b32 %0, %1" : "+v"(y2), "+v"(w2));
    u32x4 f2 = {x2, y2, z2, w2};
    pfs[2] = __builtin_bit_cast(bf16x8, f2);
    unsigned x3 = pkbf(p1[8], p1[9]), y3 = pkbf(p1[10], p1[11]);
    unsigned z3 = pkbf(p1[12], p1[13]), w3 = pkbf(p1[14], p1[15]);
    asm("v_permlane32_swap_b32 %0, %1" : "+v"(x3), "+v"(z3));
    asm("v_permlane32_swap_b32 %0, %1" : "+v"(y3), "+v"(w3));
    u32x4 f3 = {x3, y3, z3, w3};
    pfs[3] = __builtin_bit_cast(bf16x8, f3);
  };

  stageK(0, 0);
  __syncthreads();
  int cur = 0;

  for (int T = 0; T < 16; ++T) {
    if (T < 15) stageK(cur ^ 1, (T + 1) * 128);
    bf16x8 vfa[8], vfb[8];
    ldV(2 * T, vfa);
    ldV(2 * T + 1, vfb);
    const char* sKc = (const char*)sK + cur * 16384;

    // S inits = additive mask rows (broadcast LDS reads); A = rows 0..63, B = 64..127
    f32x16 s0a, s1a, s0b, s1b;
#pragma unroll
    for (int g = 0; g < 4; ++g) {
      f32x4 a0 = *(const f32x4*)(saddm + T * 128 + g * 8 + h5 * 4);
      f32x4 a1 = *(const f32x4*)(saddm + T * 128 + 32 + g * 8 + h5 * 4);
      f32x4 b0 = *(const f32x4*)(saddm + T * 128 + 64 + g * 8 + h5 * 4);
      f32x4 b1 = *(const f32x4*)(saddm + T * 128 + 96 + g * 8 + h5 * 4);
#pragma unroll
      for (int j = 0; j < 4; ++j) {
        s0a[g * 4 + j] = a0[j]; s1a[g * 4 + j] = a1[j];
        s0b[g * 4 + j] = b0[j]; s1b[g * 4 + j] = b1[j];
      }
    }

    // S^T += K . Q — 4 interleaved independent chains
#pragma unroll
    for (int ks = 0; ks < 4; ++ks) {
      const int sl = (((ks * 2 + h5) ^ (l31 & 7)) * 16);
      bf16x8 k0a = *(const bf16x8*)(sKc + l31 * 128 + sl);
      bf16x8 k1a = *(const bf16x8*)(sKc + (32 + l31) * 128 + sl);
      bf16x8 k0b = *(const bf16x8*)(sKc + (64 + l31) * 128 + sl);
      bf16x8 k1b = *(const bf16x8*)(sKc + (96 + l31) * 128 + sl);
      s0a = __builtin_amdgcn_mfma_f32_32x32x16_bf16(k0a, qf[ks], s0a, 0, 0, 0);
      s1a = __builtin_amdgcn_mfma_f32_32x32x16_bf16(k1a, qf[ks], s1a, 0, 0, 0);
      s0b = __builtin_amdgcn_mfma_f32_32x32x16_bf16(k0b, qf[ks], s0b, 0, 0, 0);
      s1b = __builtin_amdgcn_mfma_f32_32x32x16_bf16(k1b, qf[ks], s1b, 0, 0, 0);
    }

    // single max over all 128 rows (log2 domain), defer-max THR=11
    f32x16 mx;
#pragma unroll
    for (int r = 0; r < 16; ++r)
      mx[r] = fmaxf(fmaxf(s0a[r], s1a[r]), fmaxf(s0b[r], s1b[r]));
    float t8[8];
#pragma unroll
    for (int r = 0; r < 8; ++r) t8[r] = fmaxf(mx[r], mx[r + 8]);
    float tp = fmaxf(fmaxf(fmaxf(t8[0], t8[1]), fmaxf(t8[2], t8[3])),
                     fmaxf(fmaxf(t8[4], t8[5]), fmaxf(t8[6], t8[7])));
    {
      float ta = tp, tb = tp;
      asm("v_permlane32_swap_b32 %0, %1" : "+v"(ta), "+v"(tb));
      tp = fmaxf(ta, tb);
    }
    if (__any(tp > m_ + 11.0f)) {
      const float mnew = fmaxf(m_, tp);
      const float corr = EXP2(m_ - mnew);
      m_ = mnew;
      l_vec *= corr; o0 *= corr; o1 *= corr;
    }

    // P = 2^(S - m), in place
#pragma unroll
    for (int r = 0; r < 16; ++r) s0a[r] = EXP2(s0a[r] - m_);
#pragma unroll
    for (int r = 0; r < 16; ++r) s1a[r] = EXP2(s1a[r] - m_);
#pragma unroll
    for (int r = 0; r < 16; ++r) s0b[r] = EXP2(s0b[r] - m_);
#pragma unroll
    for (int r = 0; r < 16; ++r) s1b[r] = EXP2(s1b[r] - m_);
    l_vec += s0a; l_vec += s1a; l_vec += s0b; l_vec += s1b;

    // stream A: build fragments, PV (pfsA/vfa die before pfsB lives)
    {
      bf16x8 pfsA[4];
      mkpfs(s0a, s1a, pfsA);
#pragma unroll
      for (int ks = 0; ks < 4; ++ks) {
        o0 = __builtin_amdgcn_mfma_f32_32x32x16_bf16(vfa[ks * 2], pfsA[ks], o0, 0, 0, 0);
        o1 = __builtin_amdgcn_mfma_f32_32x32x16_bf16(vfa[ks * 2 + 1], pfsA[ks], o1, 0, 0, 0);
      }
    }
    // stream B
    {
      bf16x8 pfsB[4];
      mkpfs(s0b, s1b, pfsB);
#pragma unroll
      for (int ks = 0; ks < 4; ++ks) {
        o0 = __builtin_amdgcn_mfma_f32_32x32x16_bf16(vfb[ks * 2], pfsB[ks], o0, 0, 0, 0);
        o1 = __builtin_amdgcn_mfma_f32_32x32x16_bf16(vfb[ks * 2 + 1], pfsB[ks], o1, 0, 0, 0);
      }
    }
    __syncthreads();
    cur ^= 1;
  }

  // final reductions (horizontal + cross-half)
  float l_s;
  {
    float a[8];
#pragma unroll
    for (int r = 0; r < 8; ++r) a[r] = l_vec[r] + l_vec[r + 8];
    l_s = ((a[0] + a[1]) + (a[2] + a[3])) + ((a[4] + a[5]) + (a[6] + a[7]));
    float ta = l_s, tb = l_s;
    asm("v_permlane32_swap_b32 %0, %1" : "+v"(ta), "+v"(tb));
    l_s = ta + tb;
  }
  const float po = pl_s * 0.6931471805599453f / counts[b];
  const float wgv = 1.f / (1.f + __expf(-(po * gain[hh] + gbias[hh])));
  const float invl = 1.f / l_s;

  // transpose O^T -> O through wave-private swizzled LDS overlay
  __syncthreads();
  float* myOT = sOT + w * 2048;
#pragma unroll
  for (int r = 0; r < 16; ++r) {
    const int d0 = (r & 3) + 8 * (r >> 2) + 4 * h5;
    myOT[d0 * 32 + (l31 ^ (d0 & 31))] = o0[r] * invl;
    const int d1 = d0 + 32;
    myOT[d1 * 32 + (l31 ^ (d1 & 31))] = o1[r] * invl;
  }
  __syncthreads();
  const size_t rowbase = (size_t)(b * 2048 + q0 + w * 32) * 1280 + hh * 64 + lane;
  const float* pqrow = pq + rowbase;
  float* outrow = out + rowbase;
#pragma unroll 4
  for (int i = 0; i < 32; ++i) {
    const float hval = myOT[lane * 32 + (i ^ (lane & 31))];
    const float wgrow = __shfl(wgv, i, 64);
    const float pv = pqrow[(size_t)i * 1280];
    outrow[(size_t)i * 1280] = fmaf(hval - pv, wgrow, pv);
  }
}

extern "C" void kernel_launch(void* const* d_in, const int* in_sizes, int n_in,
                              void* d_out, int out_size, void* d_ws, size_t ws_size,
                              hipStream_t stream) {
  const float* pre_vk = (const float*)d_in[0];
  const float* pre_q  = (const float*)d_in[1];
  const float* vmask  = (const float*)d_in[2];
  const float* vcnt   = (const float*)d_in[3];
  const float* Wq = (const float*)d_in[4];
  const float* bq = (const float*)d_in[5];
  const float* Wk = (const float*)d_in[6];
  const float* bk = (const float*)d_in[7];
  const float* Wv = (const float*)d_in[8];
  const float* bv = (const float*)d_in[9];
  const float* gain  = (const float*)d_in[10];
  const float* gbias = (const float*)d_in[11];
  float* out = (float*)d_out;

  char* ws = (char*)d_ws;
  unsigned short* pq_bf = (unsigned short*)(ws);              // 4096x1280 bf16
  unsigned short* pv_bf = (unsigned short*)(ws + 10485760);   // 4096x1024
  unsigned short* WqT   = (unsigned short*)(ws + 18874368);   // 1024x1280
  unsigned short* WkT   = (unsigned short*)(ws + 21495808);   // 1024x1024
  unsigned short* WvT   = (unsigned short*)(ws + 23592960);   // 1024x1024
  unsigned short* Qb    = (unsigned short*)(ws + 25690112);   // 4096x1024 (0.125*log2e scaled)
  unsigned short* Kbb   = (unsigned short*)(ws + 34078720);   // 4096x1024 row-major K
  unsigned short* VFb   = (unsigned short*)(ws + 42467328);   // frag-ordered V^T, 8 MB
  float*          kmb   = (float*)(ws + 50855936);            // (2,16,64)
  float*          addm  = (float*)(ws + 50864128);            // (2,2048) f32

  hipMemsetAsync(kmb, 0, 2 * 16 * 64 * sizeof(float), stream);
  cvt_pq_tail<<<5120, 256, 0, stream>>>(pre_q, pq_bf, out);
  cvt_f32_bf16<<<4096, 256, 0, stream>>>(pre_vk, pv_bf, 1048576);
  transpose_w3<<<dim3(32, 40, 3), 256, 0, stream>>>(Wq, Wk, Wv, WqT, WkT, WvT);
  gemm_all<<<dim3(32, 8, 3), 256, 0, stream>>>(pq_bf, pv_bf, WqT, WkT, WvT, bq, bk, bv, Qb, Kbb, VFb);
  km_reduce<<<256, 256, 0, stream>>>(Kbb, vmask, kmb, addm);
  attn_fused<<<512, 256, 0, stream>>>(Qb, Kbb, VFb, addm, kmb, vcnt, gain, gbias, pre_q, out);
}

// Round 12
// 115.021 us; speedup vs baseline: 1.0551x; 1.0551x over previous
//
#include <hip/hip_runtime.h>

// ---------- types ----------
typedef __attribute__((ext_vector_type(8))) __bf16 bf16x8;
typedef __attribute__((ext_vector_type(4))) float f32x4;
typedef __attribute__((ext_vector_type(16))) float f32x16;
typedef __attribute__((ext_vector_type(4))) unsigned short us4;
typedef __attribute__((ext_vector_type(4))) unsigned int u32x4;
typedef __attribute__((address_space(3))) void* as3vp;
typedef const __attribute__((address_space(1))) void* as1vp;

#define GLOAD_LDS16(g, l) __builtin_amdgcn_global_load_lds((as1vp)(g), (as3vp)(l), 16, 0, 0)

#if __has_builtin(__builtin_amdgcn_exp2f)
#define EXP2(x) __builtin_amdgcn_exp2f(x)
#else
#define EXP2(x) __expf((x) * 0.6931471805599453f)
#endif

__device__ __forceinline__ unsigned short f2bf(float f) {
  unsigned u = __builtin_bit_cast(unsigned, f);
  u += 0x7FFFu + ((u >> 16) & 1u);   // RNE
  return (unsigned short)(u >> 16);
}
__device__ __forceinline__ float bf2f(unsigned short u) {
  return __builtin_bit_cast(float, (unsigned)u << 16);
}
__device__ __forceinline__ unsigned int pkbf(float a, float b) {
  unsigned int r;
  asm("v_cvt_pk_bf16_f32 %0, %1, %2" : "=v"(r) : "v"(a), "v"(b));
  return r;
}

// ---------- fused prep: pq cvt+tail, pv cvt, 3x weight transpose ----------
// grid partition: [0,5120) pq cvt + out-tail; [5120,9216) pv cvt;
// [9216,13056) weight transpose (z = (bid-9216)/1280).
__global__ void prep_all(const float* __restrict__ pre_q, const float* __restrict__ pre_vk,
                         const float* __restrict__ Wq, const float* __restrict__ Wk,
                         const float* __restrict__ Wv,
                         unsigned short* __restrict__ pq_bf, unsigned short* __restrict__ pv_bf,
                         unsigned short* __restrict__ WqT, unsigned short* __restrict__ WkT,
                         unsigned short* __restrict__ WvT, float* __restrict__ out) {
  __shared__ float tsh[32][33];
  const int bid = blockIdx.x, tid = threadIdx.x;
  if (bid < 5120) {
    const int i = bid * 256 + tid;                 // < 1310720
    float4 v = ((const float4*)pre_q)[i];
    us4 o;
    o.x = f2bf(v.x); o.y = f2bf(v.y); o.z = f2bf(v.z); o.w = f2bf(v.w);
    ((us4*)pq_bf)[i] = o;
    if ((i % 320) >= 256) ((float4*)out)[i] = v;   // tail passthrough
  } else if (bid < 9216) {
    const int i = (bid - 5120) * 256 + tid;        // < 1048576
    float4 v = ((const float4*)pre_vk)[i];
    us4 o;
    o.x = f2bf(v.x); o.y = f2bf(v.y); o.z = f2bf(v.z); o.w = f2bf(v.w);
    ((us4*)pv_bf)[i] = o;
  } else {
    const int tb = bid - 9216;                     // < 3840
    const int z = tb / 1280, rem = tb % 1280;
    const int x = rem & 31, y = rem >> 5;          // y < 40
    const int K = (z == 0) ? 1280 : 1024;
    if (y * 32 >= K) return;
    const float* W = (z == 0) ? Wq : ((z == 1) ? Wk : Wv);
    unsigned short* WT = (z == 0) ? WqT : ((z == 1) ? WkT : WvT);
    const int tx = tid & 31, ty = tid >> 5;
    const int n0 = x * 32, k0 = y * 32;
#pragma unroll
    for (int i = 0; i < 32; i += 8)
      tsh[ty + i][tx] = W[(size_t)(k0 + ty + i) * 1024 + n0 + tx];
    __syncthreads();
#pragma unroll
    for (int i = 0; i < 32; i += 8)
      WT[(size_t)(n0 + ty + i) * K + k0 + tx] = f2bf(tsh[tx][ty + i]);
  }
}

// ---------- km reduce (atomic, 256 blocks) + addm (f32) production ----------
__global__ void km_reduce(const unsigned short* __restrict__ Kbb, const float* __restrict__ mask,
                          float* __restrict__ km, float* __restrict__ addm) {
  if (blockIdx.x < 16) {
    const int i = blockIdx.x * 256 + threadIdx.x;   // 0..4095
    addm[i] = (mask[i] != 0.f) ? 0.f : -1e30f;
  }
  __shared__ float red[16][64];
  const int bh = blockIdx.x >> 3, chunk = blockIdx.x & 7;
  const int b = bh >> 4;
  const int dg = (threadIdx.x & 15) * 4, rg = threadIdx.x >> 4;
  const unsigned short* kb = Kbb + (size_t)(b * 2048) * 1024 + (bh & 15) * 64 + dg;
  const float* mr = mask + b * 2048;
  float a0 = 0.f, a1 = 0.f, a2 = 0.f, a3 = 0.f;
  const int kv0 = chunk * 256;
#pragma unroll 4
  for (int kv = kv0 + rg; kv < kv0 + 256; kv += 16) {
    const float mv = mr[kv];
    us4 kq = *(const us4*)(kb + (size_t)kv * 1024);
    a0 = fmaf(mv, bf2f(kq.x), a0); a1 = fmaf(mv, bf2f(kq.y), a1);
    a2 = fmaf(mv, bf2f(kq.z), a2); a3 = fmaf(mv, bf2f(kq.w), a3);
  }
  red[rg][dg] = a0; red[rg][dg + 1] = a1; red[rg][dg + 2] = a2; red[rg][dg + 3] = a3;
  __syncthreads();
  if (threadIdx.x < 64) {
    float s = 0.f;
#pragma unroll
    for (int i = 0; i < 16; ++i) s += red[i][threadIdx.x];
    atomicAdd(&km[bh * 64 + threadIdx.x], s);
  }
}

// ---------- merged Q/K/V GEMM, 128x128 tile, BK=32 dbuf (32KB LDS, 3 blk/CU) ----------
// z=0: Q row-major (scaled 0.125*log2e). z=1: K row-major.
// z=2: V -> LDS transpose -> fragment-ordered VF stores (dense 256B runs).
// Swizzle (both-sides): store chunk pos p = kchunk ^ (r&3); read koS = (lhi^(l15&3))*8.
__global__ __launch_bounds__(256, 3)
void gemm_all(const unsigned short* __restrict__ Aq,
              const unsigned short* __restrict__ Akv,
              const unsigned short* __restrict__ WqT,
              const unsigned short* __restrict__ WkT,
              const unsigned short* __restrict__ WvT,
              const float* __restrict__ bq,
              const float* __restrict__ bk,
              const float* __restrict__ bv,
              unsigned short* __restrict__ Qout,
              unsigned short* __restrict__ Kout,
              unsigned short* __restrict__ VFout) {
  __shared__ unsigned short sAB[2][2][128 * 32];   // [buf][A/B], 32 KB total
  const int z = blockIdx.z;
  const int KDIM = (z == 0) ? 1280 : 1024;
  const unsigned short* A = (z == 0) ? Aq : Akv;
  const unsigned short* Bt = (z == 0) ? WqT : ((z == 1) ? WkT : WvT);

  const int tid = threadIdx.x, lane = tid & 63, w = tid >> 6;
  const int l15 = lane & 15, lhi = lane >> 4;
  const int wm = w >> 1, wn = w & 1;
  const int row0 = blockIdx.x * 128, col0 = blockIdx.y * 128;

  const f32x4 zv = {0.f, 0.f, 0.f, 0.f};
  f32x4 acc[4][4];
#pragma unroll
  for (int m = 0; m < 4; ++m)
#pragma unroll
    for (int n = 0; n < 4; ++n) acc[m][n] = zv;

  auto stage = [&](int buf, int kt) {
#pragma unroll
    for (int i = 0; i < 2; ++i) {
      const int c = i * 256 + tid;                 // 0..511
      const int r = c >> 2, kc = ((c & 3) ^ (r & 3)) * 8;
      GLOAD_LDS16(A + (size_t)(row0 + r) * KDIM + kt + kc, &sAB[buf][0][0] + c * 8);
      GLOAD_LDS16(Bt + (size_t)(col0 + r) * KDIM + kt + kc, &sAB[buf][1][0] + c * 8);
    }
  };

  const int NT = KDIM / 32;
  stage(0, 0);
  __syncthreads();
  int cur = 0;
  for (int t = 0; t < NT; ++t) {
    if (t + 1 < NT) stage(cur ^ 1, (t + 1) * 32);
    const unsigned short* sAb = &sAB[cur][0][0];
    const unsigned short* sBb = &sAB[cur][1][0];
    const int koS = ((lhi ^ (l15 & 3)) * 8);
    bf16x8 af[4], bfr[4];
#pragma unroll
    for (int m = 0; m < 4; ++m) af[m] = *(const bf16x8*)(sAb + (wm * 64 + m * 16 + l15) * 32 + koS);
#pragma unroll
    for (int n = 0; n < 4; ++n) bfr[n] = *(const bf16x8*)(sBb + (wn * 64 + n * 16 + l15) * 32 + koS);
#pragma unroll
    for (int m = 0; m < 4; ++m)
#pragma unroll
      for (int n = 0; n < 4; ++n)
        acc[m][n] = __builtin_amdgcn_mfma_f32_16x16x32_bf16(af[m], bfr[n], acc[m][n], 0, 0, 0);
    __syncthreads();
    cur ^= 1;
  }

  if (z <= 1) {
    unsigned short* C = (z == 0) ? Qout : Kout;
    const float* bias = (z == 0) ? bq : bk;
    const float scale = (z == 0) ? 0.18033688f : 1.0f;   // 0.125 * log2(e)
#pragma unroll
    for (int n = 0; n < 4; ++n) {
      const int gc = col0 + wn * 64 + n * 16 + l15;
      const float bb = bias[gc];
#pragma unroll
      for (int m = 0; m < 4; ++m) {
        const int gr0 = row0 + wm * 64 + m * 16 + lhi * 4;
#pragma unroll
        for (int r = 0; r < 4; ++r)
          C[(size_t)(gr0 + r) * 1024 + gc] = f2bf((acc[m][n][r] + bb) * scale);
      }
    }
  } else {
    // V: transpose 128(kv) x 128(ch) tile through LDS, then fragment-ordered stores.
    __syncthreads();
    unsigned* tb = (unsigned*)&sAB[0][0][0];       // 128 rows x 64 u32 = 32 KB
#pragma unroll
    for (int n = 0; n < 4; ++n) {
      const int gcL = wn * 64 + n * 16 + l15;      // local ch 0..127
      const float bb = bv[col0 + gcL];
#pragma unroll
      for (int m = 0; m < 4; ++m) {
#pragma unroll
        for (int k = 0; k < 2; ++k) {
          const int grPair = wm * 32 + m * 8 + lhi * 2 + k;   // kv pair 0..63
          const int W = (grPair & 3) | ((((grPair >> 2) ^ gcL) & 15) << 2);
          tb[gcL * 64 + W] = pkbf(acc[m][n][2 * k] + bb, acc[m][n][2 * k + 1] + bb);
        }
      }
    }
    __syncthreads();
    const int b_ = row0 >> 11;
#pragma unroll
    for (int it = 0; it < 8; ++it) {
      const int c = it * 256 + tid;                // 0..2047
      const int gcL = (c & 63) + ((c >> 10) << 6); // d-inner for dense frag stores
      const int u = (c >> 6) & 15;                 // kv-8-group
      const int W4 = (u ^ gcL) & 15;
      u32x4 o = *(const u32x4*)(tb + gcL * 64 + W4 * 4);
      const int kv0 = (row0 & 2047) + u * 8;
      const int ch = col0 + gcL;
      const int hh2 = ch >> 6, d = ch & 63;
      const int t2 = kv0 >> 6, ks2 = (kv0 >> 4) & 3, h5v = (kv0 >> 3) & 1;
      const size_t off = ((size_t)(b_ * 16 + hh2) << 17) +
                         (size_t)(((t2 * 4 + ks2) * 2 + (d >> 5)) * 64 + h5v * 32 + (d & 31)) * 8;
      *(u32x4*)(VFout + off) = o;
    }
  }
}

// ---------- fused flash attention + pooled gate + blend (R10 structure) ----------
// 512 blocks (XCD-swizzled bh), 256 threads = 4 waves, 32 q-rows/wave.
// HYBRID: K LDS-staged dbuf; V reg-direct from fragment-ordered VF.
__global__ __launch_bounds__(256, 2)
void attn_fused(const unsigned short* __restrict__ Q,    // (B*SQ,1024) bf16, 0.125*log2e scaled
                const unsigned short* __restrict__ Kb,   // (B*SV,1024) bf16 row-major
                const unsigned short* __restrict__ VF,   // frag-ordered V^T
                const float* __restrict__ addm_g,        // (B,SV) 0/-1e30
                const float* __restrict__ km,            // (B,H,64)
                const float* __restrict__ counts,        // (B)
                const float* __restrict__ gain,          // (H)
                const float* __restrict__ gbias,         // (H)
                const float* __restrict__ pq,            // (B*SQ,1280) f32
                float* __restrict__ out) {               // (B*SQ,1280) f32
  __shared__ __align__(16) char smem[32768];
  unsigned short* sK = (unsigned short*)smem;            // [2][64*64] 16 KB
  float* saddm = (float*)(smem + 16384);                 // [2048] 8 KB
  float* sOT = (float*)smem;                             // epilogue overlay (32 KB)

  const int tid = threadIdx.x, lane = tid & 63, w = tid >> 6;
  const int l31 = lane & 31, h5 = lane >> 5;
  const int f = blockIdx.x;
  const int qt = (f >> 3) & 15;
  const int bh = (f & 7) + 8 * (f >> 7);
  const int b = bh >> 4, hh = bh & 15;
  const int q0 = qt * 128;

  // stage additive mask (2048 f32)
  GLOAD_LDS16(addm_g + b * 2048 + tid * 4, (char*)saddm + tid * 16);
  GLOAD_LDS16(addm_g + b * 2048 + 1024 + tid * 4, (char*)saddm + 4096 + tid * 16);

  // Q fragments (B-operand): lane l31 = q col, k = ks*16 + h5*8 + j
  bf16x8 qf[4];
  {
    const unsigned short* qp = Q + (size_t)(b * 2048 + q0 + w * 32 + l31) * 1024 + hh * 64 + h5 * 8;
#pragma unroll
    for (int ks = 0; ks < 4; ++ks) qf[ks] = *(const bf16x8*)(qp + ks * 16);
  }

  // pooled = km . q (log2-scaled; corrected by ln2 in the gate)
  float pl_s = 0.f;
  {
    const float* kmp = km + (b * 16 + hh) * 64 + h5 * 8;
#pragma unroll
    for (int ks = 0; ks < 4; ++ks) {
      f32x4 ka = *(const f32x4*)(kmp + ks * 16);
      f32x4 kb4 = *(const f32x4*)(kmp + ks * 16 + 4);
#pragma unroll
      for (int j = 0; j < 4; ++j)
        pl_s += (float)qf[ks][j] * ka[j] + (float)qf[ks][j + 4] * kb4[j];
    }
    float ta = pl_s, tb = pl_s;
    asm("v_permlane32_swap_b32 %0, %1" : "+v"(ta), "+v"(tb));
    pl_s = ta + tb;
  }

  const unsigned short* Kbase = Kb + (size_t)(b * 2048) * 1024 + hh * 64;
  const unsigned short* VFb = VF + ((size_t)bh << 17) + lane * 8;

  f32x16 o0, o1, l_vec;
#pragma unroll
  for (int r = 0; r < 16; ++r) { o0[r] = 0.f; o1[r] = 0.f; l_vec[r] = 0.f; }
  float m_ = -1e30f;

  auto stageK = [&](int buf, int kv) {
#pragma unroll
    for (int i = 0; i < 2; ++i) {
      const int c = i * 256 + tid;                       // 0..511
      const int r = c >> 3, sl = (c & 7) ^ (r & 7);
      GLOAD_LDS16(Kbase + (size_t)(kv + r) * 1024 + sl * 8, (char*)sK + buf * 8192 + c * 16);
    }
  };

  bf16x8 vf[8];
  auto ldV = [&](int t) {
    const unsigned short* p = VFb + (size_t)t * 4096;
#pragma unroll
    for (int i = 0; i < 8; ++i) vf[i] = *(const bf16x8*)(p + i * 512);
  };

  stageK(0, 0);
  __syncthreads();
  int cur = 0;

  for (int t = 0; t < 32; ++t) {
    if (t < 31) stageK(cur ^ 1, (t + 1) * 64);
    ldV(t);                                              // in flight under QK+softmax
    const char* sKc = (const char*)sK + cur * 8192;

    // S^T init = additive mask rows (C-initializer; broadcast LDS reads)
    f32x16 s0, s1;
#pragma unroll
    for (int g = 0; g < 4; ++g) {
      f32x4 a0 = *(const f32x4*)(saddm + t * 64 + g * 8 + h5 * 4);
      f32x4 a1 = *(const f32x4*)(saddm + t * 64 + 32 + g * 8 + h5 * 4);
#pragma unroll
      for (int j = 0; j < 4; ++j) { s0[g * 4 + j] = a0[j]; s1[g * 4 + j] = a1[j]; }
    }

    // S^T += K . Q (rows kv, cols q=lane)
#pragma unroll
    for (int ks = 0; ks < 4; ++ks) {
      const int sl = (((ks * 2 + h5) ^ (l31 & 7)) * 16);
      bf16x8 k0 = *(const bf16x8*)(sKc + l31 * 128 + sl);
      bf16x8 k1 = *(const bf16x8*)(sKc + (32 + l31) * 128 + sl);
      s0 = __builtin_amdgcn_mfma_f32_32x32x16_bf16(k0, qf[ks], s0, 0, 0, 0);
      s1 = __builtin_amdgcn_mfma_f32_32x32x16_bf16(k1, qf[ks], s1, 0, 0, 0);
    }

    // wave max (log2 domain), defer-max THR=11 (~8 nats)
    f32x16 mx;
#pragma unroll
    for (int r = 0; r < 16; ++r) mx[r] = fmaxf(s0[r], s1[r]);
    float t8[8];
#pragma unroll
    for (int r = 0; r < 8; ++r) t8[r] = fmaxf(mx[r], mx[r + 8]);
    float tp = fmaxf(fmaxf(fmaxf(t8[0], t8[1]), fmaxf(t8[2], t8[3])),
                     fmaxf(fmaxf(t8[4], t8[5]), fmaxf(t8[6], t8[7])));
    {
      float ta = tp, tb = tp;
      asm("v_permlane32_swap_b32 %0, %1" : "+v"(ta), "+v"(tb));
      tp = fmaxf(ta, tb);
    }
    if (__any(tp > m_ + 11.0f)) {
      const float mnew = fmaxf(m_, tp);
      const float corr = EXP2(m_ - mnew);
      m_ = mnew;
      l_vec *= corr; o0 *= corr; o1 *= corr;
    }

    // P = 2^(S - m)
    f32x16 p0, p1;
#pragma unroll
    for (int r = 0; r < 16; ++r) p0[r] = EXP2(s0[r] - m_);
#pragma unroll
    for (int r = 0; r < 16; ++r) p1[r] = EXP2(s1[r] - m_);
    l_vec += p0; l_vec += p1;

    // P^T B-fragments in-register: cvt_pk + permlane32_swap
    bf16x8 pfs[4];
    {
      unsigned x0 = pkbf(p0[0], p0[1]), y0 = pkbf(p0[2], p0[3]);
      unsigned z0 = pkbf(p0[4], p0[5]), w0 = pkbf(p0[6], p0[7]);
      asm("v_permlane32_swap_b32 %0, %1" : "+v"(x0), "+v"(z0));
      asm("v_permlane32_swap_b32 %0, %1" : "+v"(y0), "+v"(w0));
      u32x4 f0 = {x0, y0, z0, w0};
      pfs[0] = __builtin_bit_cast(bf16x8, f0);
      unsigned x1 = pkbf(p0[8], p0[9]), y1 = pkbf(p0[10], p0[11]);
      unsigned z1 = pkbf(p0[12], p0[13]), w1 = pkbf(p0[14], p0[15]);
      asm("v_permlane32_swap_b32 %0, %1" : "+v"(x1), "+v"(z1));
      asm("v_permlane32_swap_b32 %0, %1" : "+v"(y1), "+v"(w1));
      u32x4 f1 = {x1, y1, z1, w1};
      pfs[1] = __builtin_bit_cast(bf16x8, f1);
      unsigned x2 = pkbf(p1[0], p1[1]), y2 = pkbf(p1[2], p1[3]);
      unsigned z2 = pkbf(p1[4], p1[5]), w2 = pkbf(p1[6], p1[7]);
      asm("v_permlane32_swap_b32 %0, %1" : "+v"(x2), "+v"(z2));
      asm("v_permlane32_swap_b32 %0, %1" : "+v"(y2), "+v"(w2));
      u32x4 f2 = {x2, y2, z2, w2};
      pfs[2] = __builtin_bit_cast(bf16x8, f2);
      unsigned x3 = pkbf(p1[8], p1[9]), y3 = pkbf(p1[10], p1[11]);
      unsigned z3 = pkbf(p1[12], p1[13]), w3 = pkbf(p1[14], p1[15]);
      asm("v_permlane32_swap_b32 %0, %1" : "+v"(x3), "+v"(z3));
      asm("v_permlane32_swap_b32 %0, %1" : "+v"(y3), "+v"(w3));
      u32x4 f3 = {x3, y3, z3, w3};
      pfs[3] = __builtin_bit_cast(bf16x8, f3);
    }

    // O^T += V^T . P^T  (V from registers, frag-ordered global)
#pragma unroll
    for (int ks = 0; ks < 4; ++ks) {
      o0 = __builtin_amdgcn_mfma_f32_32x32x16_bf16(vf[ks * 2], pfs[ks], o0, 0, 0, 0);
      o1 = __builtin_amdgcn_mfma_f32_32x32x16_bf16(vf[ks * 2 + 1], pfs[ks], o1, 0, 0, 0);
    }
    __syncthreads();
    cur ^= 1;
  }

  // final reductions (horizontal + cross-half)
  float l_s;
  {
    float a[8];
#pragma unroll
    for (int r = 0; r < 8; ++r) a[r] = l_vec[r] + l_vec[r + 8];
    l_s = ((a[0] + a[1]) + (a[2] + a[3])) + ((a[4] + a[5]) + (a[6] + a[7]));
    float ta = l_s, tb = l_s;
    asm("v_permlane32_swap_b32 %0, %1" : "+v"(ta), "+v"(tb));
    l_s = ta + tb;
  }
  const float po = pl_s * 0.6931471805599453f / counts[b];
  const float wgv = 1.f / (1.f + __expf(-(po * gain[hh] + gbias[hh])));
  const float invl = 1.f / l_s;

  // transpose O^T -> O through wave-private swizzled LDS overlay
  __syncthreads();
  float* myOT = sOT + w * 2048;
#pragma unroll
  for (int r = 0; r < 16; ++r) {
    const int d0 = (r & 3) + 8 * (r >> 2) + 4 * h5;
    myOT[d0 * 32 + (l31 ^ (d0 & 31))] = o0[r] * invl;
    const int d1 = d0 + 32;
    myOT[d1 * 32 + (l31 ^ (d1 & 31))] = o1[r] * invl;
  }
  __syncthreads();
  const size_t rowbase = (size_t)(b * 2048 + q0 + w * 32) * 1280 + hh * 64 + lane;
  const float* pqrow = pq + rowbase;
  float* outrow = out + rowbase;
#pragma unroll 4
  for (int i = 0; i < 32; ++i) {
    const float hval = myOT[lane * 32 + (i ^ (lane & 31))];
    const float wgrow = __shfl(wgv, i, 64);
    const float pv = pqrow[(size_t)i * 1280];
    outrow[(size_t)i * 1280] = fmaf(hval - pv, wgrow, pv);
  }
}

extern "C" void kernel_launch(void* const* d_in, const int* in_sizes, int n_in,
                              void* d_out, int out_size, void* d_ws, size_t ws_size,
                              hipStream_t stream) {
  const float* pre_vk = (const float*)d_in[0];
  const float* pre_q  = (const float*)d_in[1];
  const float* vmask  = (const float*)d_in[2];
  const float* vcnt   = (const float*)d_in[3];
  const float* Wq = (const float*)d_in[4];
  const float* bq = (const float*)d_in[5];
  const float* Wk = (const float*)d_in[6];
  const float* bk = (const float*)d_in[7];
  const float* Wv = (const float*)d_in[8];
  const float* bv = (const float*)d_in[9];
  const float* gain  = (const float*)d_in[10];
  const float* gbias = (const float*)d_in[11];
  float* out = (float*)d_out;

  char* ws = (char*)d_ws;
  unsigned short* pq_bf = (unsigned short*)(ws);              // 4096x1280 bf16
  unsigned short* pv_bf = (unsigned short*)(ws + 10485760);   // 4096x1024
  unsigned short* WqT   = (unsigned short*)(ws + 18874368);   // 1024x1280
  unsigned short* WkT   = (unsigned short*)(ws + 21495808);   // 1024x1024
  unsigned short* WvT   = (unsigned short*)(ws + 23592960);   // 1024x1024
  unsigned short* Qb    = (unsigned short*)(ws + 25690112);   // 4096x1024 (0.125*log2e scaled)
  unsigned short* Kbb   = (unsigned short*)(ws + 34078720);   // 4096x1024 row-major K
  unsigned short* VFb   = (unsigned short*)(ws + 42467328);   // frag-ordered V^T, 8 MB
  float*          kmb   = (float*)(ws + 50855936);            // (2,16,64)
  float*          addm  = (float*)(ws + 50864128);            // (2,2048) f32

  hipMemsetAsync(kmb, 0, 2 * 16 * 64 * sizeof(float), stream);
  prep_all<<<13056, 256, 0, stream>>>(pre_q, pre_vk, Wq, Wk, Wv,
                                      pq_bf, pv_bf, WqT, WkT, WvT, out);
  gemm_all<<<dim3(32, 8, 3), 256, 0, stream>>>(pq_bf, pv_bf, WqT, WkT, WvT, bq, bk, bv, Qb, Kbb, VFb);
  km_reduce<<<256, 256, 0, stream>>>(Kbb, vmask, kmb, addm);
  attn_fused<<<512, 256, 0, stream>>>(Qb, Kbb, VFb, addm, kmb, vcnt, gain, gbias, pre_q, out);
}

// Round 13
// 111.845 us; speedup vs baseline: 1.0851x; 1.0284x over previous
//
#include <hip/hip_runtime.h>

// ---------- types ----------
typedef __attribute__((ext_vector_type(8))) __bf16 bf16x8;
typedef __attribute__((ext_vector_type(4))) float f32x4;
typedef __attribute__((ext_vector_type(16))) float f32x16;
typedef __attribute__((ext_vector_type(4))) unsigned short us4;
typedef __attribute__((ext_vector_type(4))) unsigned int u32x4;
typedef __attribute__((address_space(3))) void* as3vp;
typedef const __attribute__((address_space(1))) void* as1vp;

#define GLOAD_LDS16(g, l) __builtin_amdgcn_global_load_lds((as1vp)(g), (as3vp)(l), 16, 0, 0)

#if __has_builtin(__builtin_amdgcn_exp2f)
#define EXP2(x) __builtin_amdgcn_exp2f(x)
#else
#define EXP2(x) __expf((x) * 0.6931471805599453f)
#endif

__device__ __forceinline__ unsigned short f2bf(float f) {
  unsigned u = __builtin_bit_cast(unsigned, f);
  u += 0x7FFFu + ((u >> 16) & 1u);   // RNE
  return (unsigned short)(u >> 16);
}
__device__ __forceinline__ float bf2f(unsigned short u) {
  return __builtin_bit_cast(float, (unsigned)u << 16);
}
__device__ __forceinline__ unsigned int pkbf(float a, float b) {
  unsigned int r;
  asm("v_cvt_pk_bf16_f32 %0, %1, %2" : "=v"(r) : "v"(a), "v"(b));
  return r;
}

// ---------- fused prep: pq cvt+tail, pv cvt, 3x weight transpose, addm ----------
// grid partition: [0,5120) pq cvt + out-tail; [5120,9216) pv cvt;
// [9216,13056) weight transpose (z = (bid-9216)/1280); [13056,13072) addm.
__global__ void prep_all(const float* __restrict__ pre_q, const float* __restrict__ pre_vk,
                         const float* __restrict__ Wq, const float* __restrict__ Wk,
                         const float* __restrict__ Wv, const float* __restrict__ vmask,
                         unsigned short* __restrict__ pq_bf, unsigned short* __restrict__ pv_bf,
                         unsigned short* __restrict__ WqT, unsigned short* __restrict__ WkT,
                         unsigned short* __restrict__ WvT, float* __restrict__ addm,
                         float* __restrict__ out) {
  __shared__ float tsh[32][33];
  const int bid = blockIdx.x, tid = threadIdx.x;
  if (bid < 5120) {
    const int i = bid * 256 + tid;                 // < 1310720
    float4 v = ((const float4*)pre_q)[i];
    us4 o;
    o.x = f2bf(v.x); o.y = f2bf(v.y); o.z = f2bf(v.z); o.w = f2bf(v.w);
    ((us4*)pq_bf)[i] = o;
    if ((i % 320) >= 256) ((float4*)out)[i] = v;   // tail passthrough
  } else if (bid < 9216) {
    const int i = (bid - 5120) * 256 + tid;        // < 1048576
    float4 v = ((const float4*)pre_vk)[i];
    us4 o;
    o.x = f2bf(v.x); o.y = f2bf(v.y); o.z = f2bf(v.z); o.w = f2bf(v.w);
    ((us4*)pv_bf)[i] = o;
  } else if (bid < 13056) {
    const int tb = bid - 9216;                     // < 3840
    const int z = tb / 1280, rem = tb % 1280;
    const int x = rem & 31, y = rem >> 5;          // y < 40
    const int K = (z == 0) ? 1280 : 1024;
    if (y * 32 >= K) return;
    const float* W = (z == 0) ? Wq : ((z == 1) ? Wk : Wv);
    unsigned short* WT = (z == 0) ? WqT : ((z == 1) ? WkT : WvT);
    const int tx = tid & 31, ty = tid >> 5;
    const int n0 = x * 32, k0 = y * 32;
#pragma unroll
    for (int i = 0; i < 32; i += 8)
      tsh[ty + i][tx] = W[(size_t)(k0 + ty + i) * 1024 + n0 + tx];
    __syncthreads();
#pragma unroll
    for (int i = 0; i < 32; i += 8)
      WT[(size_t)(n0 + ty + i) * K + k0 + tx] = f2bf(tsh[tx][ty + i]);
  } else {
    const int i = (bid - 13056) * 256 + tid;       // < 4096
    addm[i] = (vmask[i] != 0.f) ? 0.f : -1e30f;
  }
}

// ---------- merged Q/K/V GEMM, 128x128 tile, BK=32 dbuf (32KB LDS, 3 blk/CU) ----------
// flat 1D grid 768, z = f%3 (interleaves Q/K/V per CU to balance Q's KDIM=1280).
// z=0: Q row-major (scaled 0.125*log2e). z=1: K row-major + FUSED km atomic reduce.
// z=2: V -> LDS transpose -> fragment-ordered VF stores (dense 256B runs).
__global__ __launch_bounds__(256, 3)
void gemm_all(const unsigned short* __restrict__ Aq,
              const unsigned short* __restrict__ Akv,
              const unsigned short* __restrict__ WqT,
              const unsigned short* __restrict__ WkT,
              const unsigned short* __restrict__ WvT,
              const float* __restrict__ bq,
              const float* __restrict__ bk,
              const float* __restrict__ bv,
              const float* __restrict__ vmask,
              unsigned short* __restrict__ Qout,
              unsigned short* __restrict__ Kout,
              unsigned short* __restrict__ VFout,
              float* __restrict__ km) {
  __shared__ unsigned short sAB[2][2][128 * 32];   // [buf][A/B], 32 KB total
  const int fblk = blockIdx.x;
  const int z = fblk % 3;
  const int rest = fblk / 3;                       // 0..255
  const int bx = rest & 31, by = rest >> 5;        // 32 row-blocks x 8 col-blocks
  const int KDIM = (z == 0) ? 1280 : 1024;
  const unsigned short* A = (z == 0) ? Aq : Akv;
  const unsigned short* Bt = (z == 0) ? WqT : ((z == 1) ? WkT : WvT);

  const int tid = threadIdx.x, lane = tid & 63, w = tid >> 6;
  const int l15 = lane & 15, lhi = lane >> 4;
  const int wm = w >> 1, wn = w & 1;
  const int row0 = bx * 128, col0 = by * 128;

  const f32x4 zv = {0.f, 0.f, 0.f, 0.f};
  f32x4 acc[4][4];
#pragma unroll
  for (int m = 0; m < 4; ++m)
#pragma unroll
    for (int n = 0; n < 4; ++n) acc[m][n] = zv;

  auto stage = [&](int buf, int kt) {
#pragma unroll
    for (int i = 0; i < 2; ++i) {
      const int c = i * 256 + tid;                 // 0..511
      const int r = c >> 2, kc = ((c & 3) ^ (r & 3)) * 8;
      GLOAD_LDS16(A + (size_t)(row0 + r) * KDIM + kt + kc, &sAB[buf][0][0] + c * 8);
      GLOAD_LDS16(Bt + (size_t)(col0 + r) * KDIM + kt + kc, &sAB[buf][1][0] + c * 8);
    }
  };

  const int NT = KDIM / 32;
  stage(0, 0);
  __syncthreads();
  int cur = 0;
  for (int t = 0; t < NT; ++t) {
    if (t + 1 < NT) stage(cur ^ 1, (t + 1) * 32);
    const unsigned short* sAb = &sAB[cur][0][0];
    const unsigned short* sBb = &sAB[cur][1][0];
    const int koS = ((lhi ^ (l15 & 3)) * 8);
    bf16x8 af[4], bfr[4];
#pragma unroll
    for (int m = 0; m < 4; ++m) af[m] = *(const bf16x8*)(sAb + (wm * 64 + m * 16 + l15) * 32 + koS);
#pragma unroll
    for (int n = 0; n < 4; ++n) bfr[n] = *(const bf16x8*)(sBb + (wn * 64 + n * 16 + l15) * 32 + koS);
#pragma unroll
    for (int m = 0; m < 4; ++m)
#pragma unroll
      for (int n = 0; n < 4; ++n)
        acc[m][n] = __builtin_amdgcn_mfma_f32_16x16x32_bf16(af[m], bfr[n], acc[m][n], 0, 0, 0);
    __syncthreads();
    cur ^= 1;
  }

  if (z == 0) {
#pragma unroll
    for (int n = 0; n < 4; ++n) {
      const int gc = col0 + wn * 64 + n * 16 + l15;
      const float bb = bq[gc];
#pragma unroll
      for (int m = 0; m < 4; ++m) {
        const int gr0 = row0 + wm * 64 + m * 16 + lhi * 4;
#pragma unroll
        for (int r = 0; r < 4; ++r)
          Qout[(size_t)(gr0 + r) * 1024 + gc] = f2bf((acc[m][n][r] + bb) * 0.18033688f);
      }
    }
  } else if (z == 1) {
    // K row-major + fused masked column-sum (km) via wave-reduce + atomicAdd
    const int b_ = row0 >> 11;
    const float* maskb = vmask + b_ * 2048;
    f32x4 mv[4];
#pragma unroll
    for (int m = 0; m < 4; ++m)
      mv[m] = *(const f32x4*)(maskb + (row0 & 2047) + wm * 64 + m * 16 + lhi * 4);
#pragma unroll
    for (int n = 0; n < 4; ++n) {
      const int gc = col0 + wn * 64 + n * 16 + l15;
      const float bb = bk[gc];
      float s = 0.f;
#pragma unroll
      for (int m = 0; m < 4; ++m) {
        const int gr0 = row0 + wm * 64 + m * 16 + lhi * 4;
#pragma unroll
        for (int r = 0; r < 4; ++r) {
          const float val = acc[m][n][r] + bb;
          Kout[(size_t)(gr0 + r) * 1024 + gc] = f2bf(val);
          s = fmaf(mv[m][r], val, s);
        }
      }
      // reduce across the 4 lanes sharing this column (lane bits 4,5)
      s += __shfl_xor(s, 16, 64);
      s += __shfl_xor(s, 32, 64);
      if (lhi == 0) atomicAdd(&km[(b_ * 16 + (gc >> 6)) * 64 + (gc & 63)], s);
    }
  } else {
    // V: transpose 128(kv) x 128(ch) tile through LDS, then fragment-ordered stores.
    __syncthreads();
    unsigned* tb = (unsigned*)&sAB[0][0][0];       // 128 rows x 64 u32 = 32 KB
#pragma unroll
    for (int n = 0; n < 4; ++n) {
      const int gcL = wn * 64 + n * 16 + l15;      // local ch 0..127
      const float bb = bv[col0 + gcL];
#pragma unroll
      for (int m = 0; m < 4; ++m) {
#pragma unroll
        for (int k = 0; k < 2; ++k) {
          const int grPair = wm * 32 + m * 8 + lhi * 2 + k;   // kv pair 0..63
          const int W = (grPair & 3) | ((((grPair >> 2) ^ gcL) & 15) << 2);
          tb[gcL * 64 + W] = pkbf(acc[m][n][2 * k] + bb, acc[m][n][2 * k + 1] + bb);
        }
      }
    }
    __syncthreads();
    const int b_ = row0 >> 11;
#pragma unroll
    for (int it = 0; it < 8; ++it) {
      const int c = it * 256 + tid;                // 0..2047
      const int gcL = (c & 63) + ((c >> 10) << 6); // d-inner for dense frag stores
      const int u = (c >> 6) & 15;                 // kv-8-group
      const int W4 = (u ^ gcL) & 15;
      u32x4 o = *(const u32x4*)(tb + gcL * 64 + W4 * 4);
      const int kv0 = (row0 & 2047) + u * 8;
      const int ch = col0 + gcL;
      const int hh2 = ch >> 6, d = ch & 63;
      const int t2 = kv0 >> 6, ks2 = (kv0 >> 4) & 3, h5v = (kv0 >> 3) & 1;
      const size_t off = ((size_t)(b_ * 16 + hh2) << 17) +
                         (size_t)(((t2 * 4 + ks2) * 2 + (d >> 5)) * 64 + h5v * 32 + (d & 31)) * 8;
      *(u32x4*)(VFout + off) = o;
    }
  }
}

// ---------- fused flash attention + pooled gate + blend (R10 structure) ----------
// 512 blocks (XCD-swizzled bh), 256 threads = 4 waves, 32 q-rows/wave.
// HYBRID: K LDS-staged dbuf; V reg-direct from fragment-ordered VF.
__global__ __launch_bounds__(256, 2)
void attn_fused(const unsigned short* __restrict__ Q,    // (B*SQ,1024) bf16, 0.125*log2e scaled
                const unsigned short* __restrict__ Kb,   // (B*SV,1024) bf16 row-major
                const unsigned short* __restrict__ VF,   // frag-ordered V^T
                const float* __restrict__ addm_g,        // (B,SV) 0/-1e30
                const float* __restrict__ km,            // (B,H,64)
                const float* __restrict__ counts,        // (B)
                const float* __restrict__ gain,          // (H)
                const float* __restrict__ gbias,         // (H)
                const float* __restrict__ pq,            // (B*SQ,1280) f32
                float* __restrict__ out) {               // (B*SQ,1280) f32
  __shared__ __align__(16) char smem[32768];
  unsigned short* sK = (unsigned short*)smem;            // [2][64*64] 16 KB
  float* saddm = (float*)(smem + 16384);                 // [2048] 8 KB
  float* sOT = (float*)smem;                             // epilogue overlay (32 KB)

  const int tid = threadIdx.x, lane = tid & 63, w = tid >> 6;
  const int l31 = lane & 31, h5 = lane >> 5;
  const int f = blockIdx.x;
  const int qt = (f >> 3) & 15;
  const int bh = (f & 7) + 8 * (f >> 7);
  const int b = bh >> 4, hh = bh & 15;
  const int q0 = qt * 128;

  // stage additive mask (2048 f32)
  GLOAD_LDS16(addm_g + b * 2048 + tid * 4, (char*)saddm + tid * 16);
  GLOAD_LDS16(addm_g + b * 2048 + 1024 + tid * 4, (char*)saddm + 4096 + tid * 16);

  // Q fragments (B-operand): lane l31 = q col, k = ks*16 + h5*8 + j
  bf16x8 qf[4];
  {
    const unsigned short* qp = Q + (size_t)(b * 2048 + q0 + w * 32 + l31) * 1024 + hh * 64 + h5 * 8;
#pragma unroll
    for (int ks = 0; ks < 4; ++ks) qf[ks] = *(const bf16x8*)(qp + ks * 16);
  }

  // pooled = km . q (log2-scaled; corrected by ln2 in the gate)
  float pl_s = 0.f;
  {
    const float* kmp = km + (b * 16 + hh) * 64 + h5 * 8;
#pragma unroll
    for (int ks = 0; ks < 4; ++ks) {
      f32x4 ka = *(const f32x4*)(kmp + ks * 16);
      f32x4 kb4 = *(const f32x4*)(kmp + ks * 16 + 4);
#pragma unroll
      for (int j = 0; j < 4; ++j)
        pl_s += (float)qf[ks][j] * ka[j] + (float)qf[ks][j + 4] * kb4[j];
    }
    float ta = pl_s, tb = pl_s;
    asm("v_permlane32_swap_b32 %0, %1" : "+v"(ta), "+v"(tb));
    pl_s = ta + tb;
  }

  const unsigned short* Kbase = Kb + (size_t)(b * 2048) * 1024 + hh * 64;
  const unsigned short* VFb = VF + ((size_t)bh << 17) + lane * 8;

  f32x16 o0, o1, l_vec;
#pragma unroll
  for (int r = 0; r < 16; ++r) { o0[r] = 0.f; o1[r] = 0.f; l_vec[r] = 0.f; }
  float m_ = -1e30f;

  auto stageK = [&](int buf, int kv) {
#pragma unroll
    for (int i = 0; i < 2; ++i) {
      const int c = i * 256 + tid;                       // 0..511
      const int r = c >> 3, sl = (c & 7) ^ (r & 7);
      GLOAD_LDS16(Kbase + (size_t)(kv + r) * 1024 + sl * 8, (char*)sK + buf * 8192 + c * 16);
    }
  };

  bf16x8 vf[8];
  auto ldV = [&](int t) {
    const unsigned short* p = VFb + (size_t)t * 4096;
#pragma unroll
    for (int i = 0; i < 8; ++i) vf[i] = *(const bf16x8*)(p + i * 512);
  };

  stageK(0, 0);
  __syncthreads();
  int cur = 0;

  for (int t = 0; t < 32; ++t) {
    if (t < 31) stageK(cur ^ 1, (t + 1) * 64);
    ldV(t);                                              // in flight under QK+softmax
    const char* sKc = (const char*)sK + cur * 8192;

    // S^T init = additive mask rows (C-initializer; broadcast LDS reads)
    f32x16 s0, s1;
#pragma unroll
    for (int g = 0; g < 4; ++g) {
      f32x4 a0 = *(const f32x4*)(saddm + t * 64 + g * 8 + h5 * 4);
      f32x4 a1 = *(const f32x4*)(saddm + t * 64 + 32 + g * 8 + h5 * 4);
#pragma unroll
      for (int j = 0; j < 4; ++j) { s0[g * 4 + j] = a0[j]; s1[g * 4 + j] = a1[j]; }
    }

    // S^T += K . Q (rows kv, cols q=lane)
#pragma unroll
    for (int ks = 0; ks < 4; ++ks) {
      const int sl = (((ks * 2 + h5) ^ (l31 & 7)) * 16);
      bf16x8 k0 = *(const bf16x8*)(sKc + l31 * 128 + sl);
      bf16x8 k1 = *(const bf16x8*)(sKc + (32 + l31) * 128 + sl);
      s0 = __builtin_amdgcn_mfma_f32_32x32x16_bf16(k0, qf[ks], s0, 0, 0, 0);
      s1 = __builtin_amdgcn_mfma_f32_32x32x16_bf16(k1, qf[ks], s1, 0, 0, 0);
    }

    // wave max (log2 domain), defer-max THR=11 (~8 nats)
    f32x16 mx;
#pragma unroll
    for (int r = 0; r < 16; ++r) mx[r] = fmaxf(s0[r], s1[r]);
    float t8[8];
#pragma unroll
    for (int r = 0; r < 8; ++r) t8[r] = fmaxf(mx[r], mx[r + 8]);
    float tp = fmaxf(fmaxf(fmaxf(t8[0], t8[1]), fmaxf(t8[2], t8[3])),
                     fmaxf(fmaxf(t8[4], t8[5]), fmaxf(t8[6], t8[7])));
    {
      float ta = tp, tb = tp;
      asm("v_permlane32_swap_b32 %0, %1" : "+v"(ta), "+v"(tb));
      tp = fmaxf(ta, tb);
    }
    if (__any(tp > m_ + 11.0f)) {
      const float mnew = fmaxf(m_, tp);
      const float corr = EXP2(m_ - mnew);
      m_ = mnew;
      l_vec *= corr; o0 *= corr; o1 *= corr;
    }

    // P = 2^(S - m)
    f32x16 p0, p1;
#pragma unroll
    for (int r = 0; r < 16; ++r) p0[r] = EXP2(s0[r] - m_);
#pragma unroll
    for (int r = 0; r < 16; ++r) p1[r] = EXP2(s1[r] - m_);
    l_vec += p0; l_vec += p1;

    // P^T B-fragments in-register: cvt_pk + permlane32_swap
    bf16x8 pfs[4];
    {
      unsigned x0 = pkbf(p0[0], p0[1]), y0 = pkbf(p0[2], p0[3]);
      unsigned z0 = pkbf(p0[4], p0[5]), w0 = pkbf(p0[6], p0[7]);
      asm("v_permlane32_swap_b32 %0, %1" : "+v"(x0), "+v"(z0));
      asm("v_permlane32_swap_b32 %0, %1" : "+v"(y0), "+v"(w0));
      u32x4 f0 = {x0, y0, z0, w0};
      pfs[0] = __builtin_bit_cast(bf16x8, f0);
      unsigned x1 = pkbf(p0[8], p0[9]), y1 = pkbf(p0[10], p0[11]);
      unsigned z1 = pkbf(p0[12], p0[13]), w1 = pkbf(p0[14], p0[15]);
      asm("v_permlane32_swap_b32 %0, %1" : "+v"(x1), "+v"(z1));
      asm("v_permlane32_swap_b32 %0, %1" : "+v"(y1), "+v"(w1));
      u32x4 f1 = {x1, y1, z1, w1};
      pfs[1] = __builtin_bit_cast(bf16x8, f1);
      unsigned x2 = pkbf(p1[0], p1[1]), y2 = pkbf(p1[2], p1[3]);
      unsigned z2 = pkbf(p1[4], p1[5]), w2 = pkbf(p1[6], p1[7]);
      asm("v_permlane32_swap_b32 %0, %1" : "+v"(x2), "+v"(z2));
      asm("v_permlane32_swap_b32 %0, %1" : "+v"(y2), "+v"(w2));
      u32x4 f2 = {x2, y2, z2, w2};
      pfs[2] = __builtin_bit_cast(bf16x8, f2);
      unsigned x3 = pkbf(p1[8], p1[9]), y3 = pkbf(p1[10], p1[11]);
      unsigned z3 = pkbf(p1[12], p1[13]), w3 = pkbf(p1[14], p1[15]);
      asm("v_permlane32_swap_b32 %0, %1" : "+v"(x3), "+v"(z3));
      asm("v_permlane32_swap_b32 %0, %1" : "+v"(y3), "+v"(w3));
      u32x4 f3 = {x3, y3, z3, w3};
      pfs[3] = __builtin_bit_cast(bf16x8, f3);
    }

    // O^T += V^T . P^T  (V from registers, frag-ordered global)
#pragma unroll
    for (int ks = 0; ks < 4; ++ks) {
      o0 = __builtin_amdgcn_mfma_f32_32x32x16_bf16(vf[ks * 2], pfs[ks], o0, 0, 0, 0);
      o1 = __builtin_amdgcn_mfma_f32_32x32x16_bf16(vf[ks * 2 + 1], pfs[ks], o1, 0, 0, 0);
    }
    __syncthreads();
    cur ^= 1;
  }

  // final reductions (horizontal + cross-half)
  float l_s;
  {
    float a[8];
#pragma unroll
    for (int r = 0; r < 8; ++r) a[r] = l_vec[r] + l_vec[r + 8];
    l_s = ((a[0] + a[1]) + (a[2] + a[3])) + ((a[4] + a[5]) + (a[6] + a[7]));
    float ta = l_s, tb = l_s;
    asm("v_permlane32_swap_b32 %0, %1" : "+v"(ta), "+v"(tb));
    l_s = ta + tb;
  }
  const float po = pl_s * 0.6931471805599453f / counts[b];
  const float wgv = 1.f / (1.f + __expf(-(po * gain[hh] + gbias[hh])));
  const float invl = 1.f / l_s;

  // transpose O^T -> O through wave-private swizzled LDS overlay
  __syncthreads();
  float* myOT = sOT + w * 2048;
#pragma unroll
  for (int r = 0; r < 16; ++r) {
    const int d0 = (r & 3) + 8 * (r >> 2) + 4 * h5;
    myOT[d0 * 32 + (l31 ^ (d0 & 31))] = o0[r] * invl;
    const int d1 = d0 + 32;
    myOT[d1 * 32 + (l31 ^ (d1 & 31))] = o1[r] * invl;
  }
  __syncthreads();
  const size_t rowbase = (size_t)(b * 2048 + q0 + w * 32) * 1280 + hh * 64 + lane;
  const float* pqrow = pq + rowbase;
  float* outrow = out + rowbase;
#pragma unroll 4
  for (int i = 0; i < 32; ++i) {
    const float hval = myOT[lane * 32 + (i ^ (lane & 31))];
    const float wgrow = __shfl(wgv, i, 64);
    const float pv = pqrow[(size_t)i * 1280];
    outrow[(size_t)i * 1280] = fmaf(hval - pv, wgrow, pv);
  }
}

extern "C" void kernel_launch(void* const* d_in, const int* in_sizes, int n_in,
                              void* d_out, int out_size, void* d_ws, size_t ws_size,
                              hipStream_t stream) {
  const float* pre_vk = (const float*)d_in[0];
  const float* pre_q  = (const float*)d_in[1];
  const float* vmask  = (const float*)d_in[2];
  const float* vcnt   = (const float*)d_in[3];
  const float* Wq = (const float*)d_in[4];
  const float* bq = (const float*)d_in[5];
  const float* Wk = (const float*)d_in[6];
  const float* bk = (const float*)d_in[7];
  const float* Wv = (const float*)d_in[8];
  const float* bv = (const float*)d_in[9];
  const float* gain  = (const float*)d_in[10];
  const float* gbias = (const float*)d_in[11];
  float* out = (float*)d_out;

  char* ws = (char*)d_ws;
  unsigned short* pq_bf = (unsigned short*)(ws);              // 4096x1280 bf16
  unsigned short* pv_bf = (unsigned short*)(ws + 10485760);   // 4096x1024
  unsigned short* WqT   = (unsigned short*)(ws + 18874368);   // 1024x1280
  unsigned short* WkT   = (unsigned short*)(ws + 21495808);   // 1024x1024
  unsigned short* WvT   = (unsigned short*)(ws + 23592960);   // 1024x1024
  unsigned short* Qb    = (unsigned short*)(ws + 25690112);   // 4096x1024 (0.125*log2e scaled)
  unsigned short* Kbb   = (unsigned short*)(ws + 34078720);   // 4096x1024 row-major K
  unsigned short* VFb   = (unsigned short*)(ws + 42467328);   // frag-ordered V^T, 8 MB
  float*          kmb   = (float*)(ws + 50855936);            // (2,16,64)
  float*          addm  = (float*)(ws + 50864128);            // (2,2048) f32

  hipMemsetAsync(kmb, 0, 2 * 16 * 64 * sizeof(float), stream);
  prep_all<<<13072, 256, 0, stream>>>(pre_q, pre_vk, Wq, Wk, Wv, vmask,
                                      pq_bf, pv_bf, WqT, WkT, WvT, addm, out);
  gemm_all<<<768, 256, 0, stream>>>(pq_bf, pv_bf, WqT, WkT, WvT, bq, bk, bv, vmask,
                                    Qb, Kbb, VFb, kmb);
  attn_fused<<<512, 256, 0, stream>>>(Qb, Kbb, VFb, addm, kmb, vcnt, gain, gbias, pre_q, out);
}

// Round 14
// 108.120 us; speedup vs baseline: 1.1224x; 1.0344x over previous
//
#include <hip/hip_runtime.h>

// ---------- types ----------
typedef __attribute__((ext_vector_type(8))) __bf16 bf16x8;
typedef __attribute__((ext_vector_type(4))) float f32x4;
typedef __attribute__((ext_vector_type(16))) float f32x16;
typedef __attribute__((ext_vector_type(4))) unsigned short us4;
typedef __attribute__((ext_vector_type(4))) unsigned int u32x4;
typedef __attribute__((address_space(3))) void* as3vp;
typedef const __attribute__((address_space(1))) void* as1vp;

#define GLOAD_LDS16(g, l) __builtin_amdgcn_global_load_lds((as1vp)(g), (as3vp)(l), 16, 0, 0)

#if __has_builtin(__builtin_amdgcn_exp2f)
#define EXP2(x) __builtin_amdgcn_exp2f(x)
#else
#define EXP2(x) __expf((x) * 0.6931471805599453f)
#endif

__device__ __forceinline__ unsigned short f2bf(float f) {
  unsigned u = __builtin_bit_cast(unsigned, f);
  u += 0x7FFFu + ((u >> 16) & 1u);   // RNE
  return (unsigned short)(u >> 16);
}
__device__ __forceinline__ float bf2f(unsigned short u) {
  return __builtin_bit_cast(float, (unsigned)u << 16);
}
__device__ __forceinline__ unsigned int pkbf(float a, float b) {
  unsigned int r;
  asm("v_cvt_pk_bf16_f32 %0, %1, %2" : "=v"(r) : "v"(a), "v"(b));
  return r;
}

// ---------- fused prep: pq cvt+tail, pv cvt, 3x weight transpose, addm+km0 ----------
// grid partition: [0,5120) pq cvt + out-tail; [5120,9216) pv cvt;
// [9216,13056) weight transpose; [13056,13072) addm + km zero-init.
__global__ void prep_all(const float* __restrict__ pre_q, const float* __restrict__ pre_vk,
                         const float* __restrict__ Wq, const float* __restrict__ Wk,
                         const float* __restrict__ Wv, const float* __restrict__ vmask,
                         unsigned short* __restrict__ pq_bf, unsigned short* __restrict__ pv_bf,
                         unsigned short* __restrict__ WqT, unsigned short* __restrict__ WkT,
                         unsigned short* __restrict__ WvT, float* __restrict__ addm,
                         float* __restrict__ km, float* __restrict__ out) {
  __shared__ float tsh[32][33];
  const int bid = blockIdx.x, tid = threadIdx.x;
  if (bid < 5120) {
    const int i = bid * 256 + tid;                 // < 1310720
    float4 v = ((const float4*)pre_q)[i];
    us4 o;
    o.x = f2bf(v.x); o.y = f2bf(v.y); o.z = f2bf(v.z); o.w = f2bf(v.w);
    ((us4*)pq_bf)[i] = o;
    if ((i % 320) >= 256) ((float4*)out)[i] = v;   // tail passthrough
  } else if (bid < 9216) {
    const int i = (bid - 5120) * 256 + tid;        // < 1048576
    float4 v = ((const float4*)pre_vk)[i];
    us4 o;
    o.x = f2bf(v.x); o.y = f2bf(v.y); o.z = f2bf(v.z); o.w = f2bf(v.w);
    ((us4*)pv_bf)[i] = o;
  } else if (bid < 13056) {
    const int tb = bid - 9216;                     // < 3840
    const int z = tb / 1280, rem = tb % 1280;
    const int x = rem & 31, y = rem >> 5;          // y < 40
    const int K = (z == 0) ? 1280 : 1024;
    if (y * 32 >= K) return;
    const float* W = (z == 0) ? Wq : ((z == 1) ? Wk : Wv);
    unsigned short* WT = (z == 0) ? WqT : ((z == 1) ? WkT : WvT);
    const int tx = tid & 31, ty = tid >> 5;
    const int n0 = x * 32, k0 = y * 32;
#pragma unroll
    for (int i = 0; i < 32; i += 8)
      tsh[ty + i][tx] = W[(size_t)(k0 + ty + i) * 1024 + n0 + tx];
    __syncthreads();
#pragma unroll
    for (int i = 0; i < 32; i += 8)
      WT[(size_t)(n0 + ty + i) * K + k0 + tx] = f2bf(tsh[tx][ty + i]);
  } else {
    const int i = (bid - 13056) * 256 + tid;       // < 4096
    addm[i] = (vmask[i] != 0.f) ? 0.f : -1e30f;
    if (i < 2048) km[i] = 0.f;                     // zero-init km (2*16*64)
  }
}

// ---------- merged Q/K/V GEMM, 128x128 tile, BK=32 dbuf (32KB LDS, 3 blk/CU) ----------
// flat 1D grid 768, z = f%3. z=0: Q (scaled 0.125*log2e). z=1: K + fused km reduce.
// z=2: V -> LDS transpose -> fragment-ordered VF stores.
__global__ __launch_bounds__(256, 3)
void gemm_all(const unsigned short* __restrict__ Aq,
              const unsigned short* __restrict__ Akv,
              const unsigned short* __restrict__ WqT,
              const unsigned short* __restrict__ WkT,
              const unsigned short* __restrict__ WvT,
              const float* __restrict__ bq,
              const float* __restrict__ bk,
              const float* __restrict__ bv,
              const float* __restrict__ vmask,
              unsigned short* __restrict__ Qout,
              unsigned short* __restrict__ Kout,
              unsigned short* __restrict__ VFout,
              float* __restrict__ km) {
  __shared__ unsigned short sAB[2][2][128 * 32];   // [buf][A/B], 32 KB total
  const int fblk = blockIdx.x;
  const int z = fblk % 3;
  const int rest = fblk / 3;                       // 0..255
  const int bx = rest & 31, by = rest >> 5;        // 32 row-blocks x 8 col-blocks
  const int KDIM = (z == 0) ? 1280 : 1024;
  const unsigned short* A = (z == 0) ? Aq : Akv;
  const unsigned short* Bt = (z == 0) ? WqT : ((z == 1) ? WkT : WvT);

  const int tid = threadIdx.x, lane = tid & 63, w = tid >> 6;
  const int l15 = lane & 15, lhi = lane >> 4;
  const int wm = w >> 1, wn = w & 1;
  const int row0 = bx * 128, col0 = by * 128;

  const f32x4 zv = {0.f, 0.f, 0.f, 0.f};
  f32x4 acc[4][4];
#pragma unroll
  for (int m = 0; m < 4; ++m)
#pragma unroll
    for (int n = 0; n < 4; ++n) acc[m][n] = zv;

  auto stage = [&](int buf, int kt) {
#pragma unroll
    for (int i = 0; i < 2; ++i) {
      const int c = i * 256 + tid;                 // 0..511
      const int r = c >> 2, kc = ((c & 3) ^ (r & 3)) * 8;
      GLOAD_LDS16(A + (size_t)(row0 + r) * KDIM + kt + kc, &sAB[buf][0][0] + c * 8);
      GLOAD_LDS16(Bt + (size_t)(col0 + r) * KDIM + kt + kc, &sAB[buf][1][0] + c * 8);
    }
  };

  const int NT = KDIM / 32;
  stage(0, 0);
  __syncthreads();
  int cur = 0;
  for (int t = 0; t < NT; ++t) {
    if (t + 1 < NT) stage(cur ^ 1, (t + 1) * 32);
    const unsigned short* sAb = &sAB[cur][0][0];
    const unsigned short* sBb = &sAB[cur][1][0];
    const int koS = ((lhi ^ (l15 & 3)) * 8);
    bf16x8 af[4], bfr[4];
#pragma unroll
    for (int m = 0; m < 4; ++m) af[m] = *(const bf16x8*)(sAb + (wm * 64 + m * 16 + l15) * 32 + koS);
#pragma unroll
    for (int n = 0; n < 4; ++n) bfr[n] = *(const bf16x8*)(sBb + (wn * 64 + n * 16 + l15) * 32 + koS);
#pragma unroll
    for (int m = 0; m < 4; ++m)
#pragma unroll
      for (int n = 0; n < 4; ++n)
        acc[m][n] = __builtin_amdgcn_mfma_f32_16x16x32_bf16(af[m], bfr[n], acc[m][n], 0, 0, 0);
    __syncthreads();
    cur ^= 1;
  }

  if (z == 0) {
#pragma unroll
    for (int n = 0; n < 4; ++n) {
      const int gc = col0 + wn * 64 + n * 16 + l15;
      const float bb = bq[gc];
#pragma unroll
      for (int m = 0; m < 4; ++m) {
        const int gr0 = row0 + wm * 64 + m * 16 + lhi * 4;
#pragma unroll
        for (int r = 0; r < 4; ++r)
          Qout[(size_t)(gr0 + r) * 1024 + gc] = f2bf((acc[m][n][r] + bb) * 0.18033688f);
      }
    }
  } else if (z == 1) {
    // K row-major + fused masked column-sum (km) via wave-reduce + atomicAdd
    const int b_ = row0 >> 11;
    const float* maskb = vmask + b_ * 2048;
    f32x4 mv[4];
#pragma unroll
    for (int m = 0; m < 4; ++m)
      mv[m] = *(const f32x4*)(maskb + (row0 & 2047) + wm * 64 + m * 16 + lhi * 4);
#pragma unroll
    for (int n = 0; n < 4; ++n) {
      const int gc = col0 + wn * 64 + n * 16 + l15;
      const float bb = bk[gc];
      float s = 0.f;
#pragma unroll
      for (int m = 0; m < 4; ++m) {
        const int gr0 = row0 + wm * 64 + m * 16 + lhi * 4;
#pragma unroll
        for (int r = 0; r < 4; ++r) {
          const float val = acc[m][n][r] + bb;
          Kout[(size_t)(gr0 + r) * 1024 + gc] = f2bf(val);
          s = fmaf(mv[m][r], val, s);
        }
      }
      s += __shfl_xor(s, 16, 64);
      s += __shfl_xor(s, 32, 64);
      if (lhi == 0) atomicAdd(&km[(b_ * 16 + (gc >> 6)) * 64 + (gc & 63)], s);
    }
  } else {
    // V: transpose 128(kv) x 128(ch) tile through LDS, then fragment-ordered stores.
    __syncthreads();
    unsigned* tb = (unsigned*)&sAB[0][0][0];       // 128 rows x 64 u32 = 32 KB
#pragma unroll
    for (int n = 0; n < 4; ++n) {
      const int gcL = wn * 64 + n * 16 + l15;      // local ch 0..127
      const float bb = bv[col0 + gcL];
#pragma unroll
      for (int m = 0; m < 4; ++m) {
#pragma unroll
        for (int k = 0; k < 2; ++k) {
          const int grPair = wm * 32 + m * 8 + lhi * 2 + k;   // kv pair 0..63
          const int W = (grPair & 3) | ((((grPair >> 2) ^ gcL) & 15) << 2);
          tb[gcL * 64 + W] = pkbf(acc[m][n][2 * k] + bb, acc[m][n][2 * k + 1] + bb);
        }
      }
    }
    __syncthreads();
    const int b_ = row0 >> 11;
#pragma unroll
    for (int it = 0; it < 8; ++it) {
      const int c = it * 256 + tid;                // 0..2047
      const int gcL = (c & 63) + ((c >> 10) << 6); // d-inner for dense frag stores
      const int u = (c >> 6) & 15;                 // kv-8-group
      const int W4 = (u ^ gcL) & 15;
      u32x4 o = *(const u32x4*)(tb + gcL * 64 + W4 * 4);
      const int kv0 = (row0 & 2047) + u * 8;
      const int ch = col0 + gcL;
      const int hh2 = ch >> 6, d = ch & 63;
      const int t2 = kv0 >> 6, ks2 = (kv0 >> 4) & 3, h5v = (kv0 >> 3) & 1;
      const size_t off = ((size_t)(b_ * 16 + hh2) << 17) +
                         (size_t)(((t2 * 4 + ks2) * 2 + (d >> 5)) * 64 + h5v * 32 + (d & 31)) * 8;
      *(u32x4*)(VFout + off) = o;
    }
  }
}

// ---------- fused flash attention + pooled gate + blend ----------
// 512 blocks (XCD-swizzled bh), 256 threads = 4 waves, 32 q-rows/wave.
// K: TRIPLE-buffered LDS with counted-vmcnt pipeline (T4): stage(t+2) issued
// each iter; "s_waitcnt vmcnt(2)" + raw s_barrier lets the 2-load prefetch
// ride across the barrier (no vmcnt(0) drain). V reg-direct from frag-ordered VF.
__global__ __launch_bounds__(256, 2)
void attn_fused(const unsigned short* __restrict__ Q,    // (B*SQ,1024) bf16, 0.125*log2e scaled
                const unsigned short* __restrict__ Kb,   // (B*SV,1024) bf16 row-major
                const unsigned short* __restrict__ VF,   // frag-ordered V^T
                const float* __restrict__ addm_g,        // (B,SV) 0/-1e30
                const float* __restrict__ km,            // (B,H,64)
                const float* __restrict__ counts,        // (B)
                const float* __restrict__ gain,          // (H)
                const float* __restrict__ gbias,         // (H)
                const float* __restrict__ pq,            // (B*SQ,1280) f32
                float* __restrict__ out) {               // (B*SQ,1280) f32
  __shared__ __align__(16) char smem[32768];
  unsigned short* sK = (unsigned short*)smem;            // [3][64*64] 24 KB
  float* saddm = (float*)(smem + 24576);                 // [2048] 8 KB
  float* sOT = (float*)smem;                             // epilogue overlay (32 KB)

  const int tid = threadIdx.x, lane = tid & 63, w = tid >> 6;
  const int l31 = lane & 31, h5 = lane >> 5;
  const int f = blockIdx.x;
  const int qt = (f >> 3) & 15;
  const int bh = (f & 7) + 8 * (f >> 7);
  const int b = bh >> 4, hh = bh & 15;
  const int q0 = qt * 128;

  // stage additive mask (2048 f32)
  GLOAD_LDS16(addm_g + b * 2048 + tid * 4, (char*)saddm + tid * 16);
  GLOAD_LDS16(addm_g + b * 2048 + 1024 + tid * 4, (char*)saddm + 4096 + tid * 16);

  // Q fragments (B-operand): lane l31 = q col, k = ks*16 + h5*8 + j
  bf16x8 qf[4];
  {
    const unsigned short* qp = Q + (size_t)(b * 2048 + q0 + w * 32 + l31) * 1024 + hh * 64 + h5 * 8;
#pragma unroll
    for (int ks = 0; ks < 4; ++ks) qf[ks] = *(const bf16x8*)(qp + ks * 16);
  }

  // pooled = km . q (log2-scaled; corrected by ln2 in the gate)
  float pl_s = 0.f;
  {
    const float* kmp = km + (b * 16 + hh) * 64 + h5 * 8;
#pragma unroll
    for (int ks = 0; ks < 4; ++ks) {
      f32x4 ka = *(const f32x4*)(kmp + ks * 16);
      f32x4 kb4 = *(const f32x4*)(kmp + ks * 16 + 4);
#pragma unroll
      for (int j = 0; j < 4; ++j)
        pl_s += (float)qf[ks][j] * ka[j] + (float)qf[ks][j + 4] * kb4[j];
    }
    float ta = pl_s, tb = pl_s;
    asm("v_permlane32_swap_b32 %0, %1" : "+v"(ta), "+v"(tb));
    pl_s = ta + tb;
  }

  const unsigned short* Kbase = Kb + (size_t)(b * 2048) * 1024 + hh * 64;
  const unsigned short* VFb = VF + ((size_t)bh << 17) + lane * 8;

  f32x16 o0, o1, l_vec;
#pragma unroll
  for (int r = 0; r < 16; ++r) { o0[r] = 0.f; o1[r] = 0.f; l_vec[r] = 0.f; }
  float m_ = -1e30f;

  auto stageK = [&](int buf, int kv) {
#pragma unroll
    for (int i = 0; i < 2; ++i) {
      const int c = i * 256 + tid;                       // 0..511
      const int r = c >> 3, sl = (c & 7) ^ (r & 7);
      GLOAD_LDS16(Kbase + (size_t)(kv + r) * 1024 + sl * 8, (char*)sK + buf * 8192 + c * 16);
    }
  };

  bf16x8 vf[8];
  auto ldV = [&](int t) {
    const unsigned short* p = VFb + (size_t)t * 4096;
#pragma unroll
    for (int i = 0; i < 8; ++i) vf[i] = *(const bf16x8*)(p + i * 512);
  };

  // prologue: 2-deep prefetch, full drain once
  stageK(0, 0);
  stageK(1, 64);
  __syncthreads();

  for (int t = 0; t < 32; ++t) {
    const int buf = t % 3;
    ldV(t);                                              // V in flight under QK+softmax
    __builtin_amdgcn_sched_barrier(0);                   // pin ldV before stage
    stageK((t + 2) % 3, ((t + 2) & 31) * 64);            // t>=30: dummy (dead buffer)
    const char* sKc = (const char*)sK + buf * 8192;

    // S^T init = additive mask rows (C-initializer; broadcast LDS reads)
    f32x16 s0, s1;
#pragma unroll
    for (int g = 0; g < 4; ++g) {
      f32x4 a0 = *(const f32x4*)(saddm + t * 64 + g * 8 + h5 * 4);
      f32x4 a1 = *(const f32x4*)(saddm + t * 64 + 32 + g * 8 + h5 * 4);
#pragma unroll
      for (int j = 0; j < 4; ++j) { s0[g * 4 + j] = a0[j]; s1[g * 4 + j] = a1[j]; }
    }

    // S^T += K . Q (rows kv, cols q=lane)
#pragma unroll
    for (int ks = 0; ks < 4; ++ks) {
      const int sl = (((ks * 2 + h5) ^ (l31 & 7)) * 16);
      bf16x8 k0 = *(const bf16x8*)(sKc + l31 * 128 + sl);
      bf16x8 k1 = *(const bf16x8*)(sKc + (32 + l31) * 128 + sl);
      s0 = __builtin_amdgcn_mfma_f32_32x32x16_bf16(k0, qf[ks], s0, 0, 0, 0);
      s1 = __builtin_amdgcn_mfma_f32_32x32x16_bf16(k1, qf[ks], s1, 0, 0, 0);
    }

    // wave max (log2 domain), defer-max THR=11 (~8 nats)
    f32x16 mx;
#pragma unroll
    for (int r = 0; r < 16; ++r) mx[r] = fmaxf(s0[r], s1[r]);
    float t8[8];
#pragma unroll
    for (int r = 0; r < 8; ++r) t8[r] = fmaxf(mx[r], mx[r + 8]);
    float tp = fmaxf(fmaxf(fmaxf(t8[0], t8[1]), fmaxf(t8[2], t8[3])),
                     fmaxf(fmaxf(t8[4], t8[5]), fmaxf(t8[6], t8[7])));
    {
      float ta = tp, tb = tp;
      asm("v_permlane32_swap_b32 %0, %1" : "+v"(ta), "+v"(tb));
      tp = fmaxf(ta, tb);
    }
    if (__any(tp > m_ + 11.0f)) {
      const float mnew = fmaxf(m_, tp);
      const float corr = EXP2(m_ - mnew);
      m_ = mnew;
      l_vec *= corr; o0 *= corr; o1 *= corr;
    }

    // P = 2^(S - m)
    f32x16 p0, p1;
#pragma unroll
    for (int r = 0; r < 16; ++r) p0[r] = EXP2(s0[r] - m_);
#pragma unroll
    for (int r = 0; r < 16; ++r) p1[r] = EXP2(s1[r] - m_);
    l_vec += p0; l_vec += p1;

    // P^T B-fragments in-register: cvt_pk + permlane32_swap
    bf16x8 pfs[4];
    {
      unsigned x0 = pkbf(p0[0], p0[1]), y0 = pkbf(p0[2], p0[3]);
      unsigned z0 = pkbf(p0[4], p0[5]), w0 = pkbf(p0[6], p0[7]);
      asm("v_permlane32_swap_b32 %0, %1" : "+v"(x0), "+v"(z0));
      asm("v_permlane32_swap_b32 %0, %1" : "+v"(y0), "+v"(w0));
      u32x4 f0 = {x0, y0, z0, w0};
      pfs[0] = __builtin_bit_cast(bf16x8, f0);
      unsigned x1 = pkbf(p0[8], p0[9]), y1 = pkbf(p0[10], p0[11]);
      unsigned z1 = pkbf(p0[12], p0[13]), w1 = pkbf(p0[14], p0[15]);
      asm("v_permlane32_swap_b32 %0, %1" : "+v"(x1), "+v"(z1));
      asm("v_permlane32_swap_b32 %0, %1" : "+v"(y1), "+v"(w1));
      u32x4 f1 = {x1, y1, z1, w1};
      pfs[1] = __builtin_bit_cast(bf16x8, f1);
      unsigned x2 = pkbf(p1[0], p1[1]), y2 = pkbf(p1[2], p1[3]);
      unsigned z2 = pkbf(p1[4], p1[5]), w2 = pkbf(p1[6], p1[7]);
      asm("v_permlane32_swap_b32 %0, %1" : "+v"(x2), "+v"(z2));
      asm("v_permlane32_swap_b32 %0, %1" : "+v"(y2), "+v"(w2));
      u32x4 f2 = {x2, y2, z2, w2};
      pfs[2] = __builtin_bit_cast(bf16x8, f2);
      unsigned x3 = pkbf(p1[8], p1[9]), y3 = pkbf(p1[10], p1[11]);
      unsigned z3 = pkbf(p1[12], p1[13]), w3 = pkbf(p1[14], p1[15]);
      asm("v_permlane32_swap_b32 %0, %1" : "+v"(x3), "+v"(z3));
      asm("v_permlane32_swap_b32 %0, %1" : "+v"(y3), "+v"(w3));
      u32x4 f3 = {x3, y3, z3, w3};
      pfs[3] = __builtin_bit_cast(bf16x8, f3);
    }

    // O^T += V^T . P^T  (V from registers; compiler waits vmcnt(2), stage rides)
#pragma unroll
    for (int ks = 0; ks < 4; ++ks) {
      o0 = __builtin_amdgcn_mfma_f32_32x32x16_bf16(vf[ks * 2], pfs[ks], o0, 0, 0, 0);
      o1 = __builtin_amdgcn_mfma_f32_32x32x16_bf16(vf[ks * 2 + 1], pfs[ks], o1, 0, 0, 0);
    }

    // counted-vmcnt barrier: own stage(t+1) done; stage(t+2) stays in flight
    asm volatile("s_waitcnt vmcnt(2)" ::: "memory");
    __builtin_amdgcn_sched_barrier(0);
    __builtin_amdgcn_s_barrier();
    __builtin_amdgcn_sched_barrier(0);
  }

  // final reductions (horizontal + cross-half)
  float l_s;
  {
    float a[8];
#pragma unroll
    for (int r = 0; r < 8; ++r) a[r] = l_vec[r] + l_vec[r + 8];
    l_s = ((a[0] + a[1]) + (a[2] + a[3])) + ((a[4] + a[5]) + (a[6] + a[7]));
    float ta = l_s, tb = l_s;
    asm("v_permlane32_swap_b32 %0, %1" : "+v"(ta), "+v"(tb));
    l_s = ta + tb;
  }
  const float po = pl_s * 0.6931471805599453f / counts[b];
  const float wgv = 1.f / (1.f + __expf(-(po * gain[hh] + gbias[hh])));
  const float invl = 1.f / l_s;

  // transpose O^T -> O through wave-private swizzled LDS overlay
  __syncthreads();   // FULL drain (incl. dummy stages) before overlay reuse
  float* myOT = sOT + w * 2048;
#pragma unroll
  for (int r = 0; r < 16; ++r) {
    const int d0 = (r & 3) + 8 * (r >> 2) + 4 * h5;
    myOT[d0 * 32 + (l31 ^ (d0 & 31))] = o0[r] * invl;
    const int d1 = d0 + 32;
    myOT[d1 * 32 + (l31 ^ (d1 & 31))] = o1[r] * invl;
  }
  __syncthreads();
  const size_t rowbase = (size_t)(b * 2048 + q0 + w * 32) * 1280 + hh * 64 + lane;
  const float* pqrow = pq + rowbase;
  float* outrow = out + rowbase;
#pragma unroll 4
  for (int i = 0; i < 32; ++i) {
    const float hval = myOT[lane * 32 + (i ^ (lane & 31))];
    const float wgrow = __shfl(wgv, i, 64);
    const float pv = pqrow[(size_t)i * 1280];
    outrow[(size_t)i * 1280] = fmaf(hval - pv, wgrow, pv);
  }
}

extern "C" void kernel_launch(void* const* d_in, const int* in_sizes, int n_in,
                              void* d_out, int out_size, void* d_ws, size_t ws_size,
                              hipStream_t stream) {
  const float* pre_vk = (const float*)d_in[0];
  const float* pre_q  = (const float*)d_in[1];
  const float* vmask  = (const float*)d_in[2];
  const float* vcnt   = (const float*)d_in[3];
  const float* Wq = (const float*)d_in[4];
  const float* bq = (const float*)d_in[5];
  const float* Wk = (const float*)d_in[6];
  const float* bk = (const float*)d_in[7];
  const float* Wv = (const float*)d_in[8];
  const float* bv = (const float*)d_in[9];
  const float* gain  = (const float*)d_in[10];
  const float* gbias = (const float*)d_in[11];
  float* out = (float*)d_out;

  char* ws = (char*)d_ws;
  unsigned short* pq_bf = (unsigned short*)(ws);              // 4096x1280 bf16
  unsigned short* pv_bf = (unsigned short*)(ws + 10485760);   // 4096x1024
  unsigned short* WqT   = (unsigned short*)(ws + 18874368);   // 1024x1280
  unsigned short* WkT   = (unsigned short*)(ws + 21495808);   // 1024x1024
  unsigned short* WvT   = (unsigned short*)(ws + 23592960);   // 1024x1024
  unsigned short* Qb    = (unsigned short*)(ws + 25690112);   // 4096x1024 (0.125*log2e scaled)
  unsigned short* Kbb   = (unsigned short*)(ws + 34078720);   // 4096x1024 row-major K
  unsigned short* VFb   = (unsigned short*)(ws + 42467328);   // frag-ordered V^T, 8 MB
  float*          kmb   = (float*)(ws + 50855936);            // (2,16,64)
  float*          addm  = (float*)(ws + 50864128);            // (2,2048) f32

  prep_all<<<13072, 256, 0, stream>>>(pre_q, pre_vk, Wq, Wk, Wv, vmask,
                                      pq_bf, pv_bf, WqT, WkT, WvT, addm, kmb, out);
  gemm_all<<<768, 256, 0, stream>>>(pq_bf, pv_bf, WqT, WkT, WvT, bq, bk, bv, vmask,
                                    Qb, Kbb, VFb, kmb);
  attn_fused<<<512, 256, 0, stream>>>(Qb, Kbb, VFb, addm, kmb, vcnt, gain, gbias, pre_q, out);
}

// Round 15
// 106.849 us; speedup vs baseline: 1.1358x; 1.0119x over previous
//
#include <hip/hip_runtime.h>

// ---------- types ----------
typedef __attribute__((ext_vector_type(8))) __bf16 bf16x8;
typedef __attribute__((ext_vector_type(4))) float f32x4;
typedef __attribute__((ext_vector_type(16))) float f32x16;
typedef __attribute__((ext_vector_type(4))) unsigned short us4;
typedef __attribute__((ext_vector_type(4))) unsigned int u32x4;
typedef __attribute__((address_space(3))) void* as3vp;
typedef const __attribute__((address_space(1))) void* as1vp;

#define GLOAD_LDS16(g, l) __builtin_amdgcn_global_load_lds((as1vp)(g), (as3vp)(l), 16, 0, 0)

#if __has_builtin(__builtin_amdgcn_exp2f)
#define EXP2(x) __builtin_amdgcn_exp2f(x)
#else
#define EXP2(x) __expf((x) * 0.6931471805599453f)
#endif

__device__ __forceinline__ unsigned short f2bf(float f) {
  unsigned u = __builtin_bit_cast(unsigned, f);
  u += 0x7FFFu + ((u >> 16) & 1u);   // RNE
  return (unsigned short)(u >> 16);
}
__device__ __forceinline__ float bf2f(unsigned short u) {
  return __builtin_bit_cast(float, (unsigned)u << 16);
}
__device__ __forceinline__ unsigned int pkbf(float a, float b) {
  unsigned int r;
  asm("v_cvt_pk_bf16_f32 %0, %1, %2" : "=v"(r) : "v"(a), "v"(b));
  return r;
}

// ---------- fused prep: pq cvt+tail, pv cvt, 3x weight transpose, addm+km0 ----------
__global__ void prep_all(const float* __restrict__ pre_q, const float* __restrict__ pre_vk,
                         const float* __restrict__ Wq, const float* __restrict__ Wk,
                         const float* __restrict__ Wv, const float* __restrict__ vmask,
                         unsigned short* __restrict__ pq_bf, unsigned short* __restrict__ pv_bf,
                         unsigned short* __restrict__ WqT, unsigned short* __restrict__ WkT,
                         unsigned short* __restrict__ WvT, float* __restrict__ addm,
                         float* __restrict__ km, float* __restrict__ out) {
  __shared__ float tsh[32][33];
  const int bid = blockIdx.x, tid = threadIdx.x;
  if (bid < 5120) {
    const int i = bid * 256 + tid;                 // < 1310720
    float4 v = ((const float4*)pre_q)[i];
    us4 o;
    o.x = f2bf(v.x); o.y = f2bf(v.y); o.z = f2bf(v.z); o.w = f2bf(v.w);
    ((us4*)pq_bf)[i] = o;
    if ((i % 320) >= 256) ((float4*)out)[i] = v;   // tail passthrough
  } else if (bid < 9216) {
    const int i = (bid - 5120) * 256 + tid;        // < 1048576
    float4 v = ((const float4*)pre_vk)[i];
    us4 o;
    o.x = f2bf(v.x); o.y = f2bf(v.y); o.z = f2bf(v.z); o.w = f2bf(v.w);
    ((us4*)pv_bf)[i] = o;
  } else if (bid < 13056) {
    const int tb = bid - 9216;                     // < 3840
    const int z = tb / 1280, rem = tb % 1280;
    const int x = rem & 31, y = rem >> 5;          // y < 40
    const int K = (z == 0) ? 1280 : 1024;
    if (y * 32 >= K) return;
    const float* W = (z == 0) ? Wq : ((z == 1) ? Wk : Wv);
    unsigned short* WT = (z == 0) ? WqT : ((z == 1) ? WkT : WvT);
    const int tx = tid & 31, ty = tid >> 5;
    const int n0 = x * 32, k0 = y * 32;
#pragma unroll
    for (int i = 0; i < 32; i += 8)
      tsh[ty + i][tx] = W[(size_t)(k0 + ty + i) * 1024 + n0 + tx];
    __syncthreads();
#pragma unroll
    for (int i = 0; i < 32; i += 8)
      WT[(size_t)(n0 + ty + i) * K + k0 + tx] = f2bf(tsh[tx][ty + i]);
  } else {
    const int i = (bid - 13056) * 256 + tid;       // < 4096
    addm[i] = (vmask[i] != 0.f) ? 0.f : -1e30f;
    if (i < 2048) km[i] = 0.f;                     // zero-init km (2*16*64)
  }
}

// ---------- merged Q/K/V GEMM, 128x128 tile, BK=32 dbuf (32KB LDS, 3 blk/CU) ----------
// flat 1D grid 768, z = f%3. z=0: Q (scaled 0.125*log2e). z=1: K + fused km reduce.
// z=2: V -> LDS transpose -> fragment-ordered VF stores.
__global__ __launch_bounds__(256, 3)
void gemm_all(const unsigned short* __restrict__ Aq,
              const unsigned short* __restrict__ Akv,
              const unsigned short* __restrict__ WqT,
              const unsigned short* __restrict__ WkT,
              const unsigned short* __restrict__ WvT,
              const float* __restrict__ bq,
              const float* __restrict__ bk,
              const float* __restrict__ bv,
              const float* __restrict__ vmask,
              unsigned short* __restrict__ Qout,
              unsigned short* __restrict__ Kout,
              unsigned short* __restrict__ VFout,
              float* __restrict__ km) {
  __shared__ unsigned short sAB[2][2][128 * 32];   // [buf][A/B], 32 KB total
  const int fblk = blockIdx.x;
  const int z = fblk % 3;
  const int rest = fblk / 3;                       // 0..255
  const int bx = rest & 31, by = rest >> 5;        // 32 row-blocks x 8 col-blocks
  const int KDIM = (z == 0) ? 1280 : 1024;
  const unsigned short* A = (z == 0) ? Aq : Akv;
  const unsigned short* Bt = (z == 0) ? WqT : ((z == 1) ? WkT : WvT);

  const int tid = threadIdx.x, lane = tid & 63, w = tid >> 6;
  const int l15 = lane & 15, lhi = lane >> 4;
  const int wm = w >> 1, wn = w & 1;
  const int row0 = bx * 128, col0 = by * 128;

  const f32x4 zv = {0.f, 0.f, 0.f, 0.f};
  f32x4 acc[4][4];
#pragma unroll
  for (int m = 0; m < 4; ++m)
#pragma unroll
    for (int n = 0; n < 4; ++n) acc[m][n] = zv;

  auto stage = [&](int buf, int kt) {
#pragma unroll
    for (int i = 0; i < 2; ++i) {
      const int c = i * 256 + tid;                 // 0..511
      const int r = c >> 2, kc = ((c & 3) ^ (r & 3)) * 8;
      GLOAD_LDS16(A + (size_t)(row0 + r) * KDIM + kt + kc, &sAB[buf][0][0] + c * 8);
      GLOAD_LDS16(Bt + (size_t)(col0 + r) * KDIM + kt + kc, &sAB[buf][1][0] + c * 8);
    }
  };

  const int NT = KDIM / 32;
  stage(0, 0);
  __syncthreads();
  int cur = 0;
  for (int t = 0; t < NT; ++t) {
    if (t + 1 < NT) stage(cur ^ 1, (t + 1) * 32);
    const unsigned short* sAb = &sAB[cur][0][0];
    const unsigned short* sBb = &sAB[cur][1][0];
    const int koS = ((lhi ^ (l15 & 3)) * 8);
    bf16x8 af[4], bfr[4];
#pragma unroll
    for (int m = 0; m < 4; ++m) af[m] = *(const bf16x8*)(sAb + (wm * 64 + m * 16 + l15) * 32 + koS);
#pragma unroll
    for (int n = 0; n < 4; ++n) bfr[n] = *(const bf16x8*)(sBb + (wn * 64 + n * 16 + l15) * 32 + koS);
#pragma unroll
    for (int m = 0; m < 4; ++m)
#pragma unroll
      for (int n = 0; n < 4; ++n)
        acc[m][n] = __builtin_amdgcn_mfma_f32_16x16x32_bf16(af[m], bfr[n], acc[m][n], 0, 0, 0);
    __syncthreads();
    cur ^= 1;
  }

  if (z == 0) {
#pragma unroll
    for (int n = 0; n < 4; ++n) {
      const int gc = col0 + wn * 64 + n * 16 + l15;
      const float bb = bq[gc];
#pragma unroll
      for (int m = 0; m < 4; ++m) {
        const int gr0 = row0 + wm * 64 + m * 16 + lhi * 4;
#pragma unroll
        for (int r = 0; r < 4; ++r)
          Qout[(size_t)(gr0 + r) * 1024 + gc] = f2bf((acc[m][n][r] + bb) * 0.18033688f);
      }
    }
  } else if (z == 1) {
    // K row-major + fused masked column-sum (km) via wave-reduce + atomicAdd
    const int b_ = row0 >> 11;
    const float* maskb = vmask + b_ * 2048;
    f32x4 mv[4];
#pragma unroll
    for (int m = 0; m < 4; ++m)
      mv[m] = *(const f32x4*)(maskb + (row0 & 2047) + wm * 64 + m * 16 + lhi * 4);
#pragma unroll
    for (int n = 0; n < 4; ++n) {
      const int gc = col0 + wn * 64 + n * 16 + l15;
      const float bb = bk[gc];
      float s = 0.f;
#pragma unroll
      for (int m = 0; m < 4; ++m) {
        const int gr0 = row0 + wm * 64 + m * 16 + lhi * 4;
#pragma unroll
        for (int r = 0; r < 4; ++r) {
          const float val = acc[m][n][r] + bb;
          Kout[(size_t)(gr0 + r) * 1024 + gc] = f2bf(val);
          s = fmaf(mv[m][r], val, s);
        }
      }
      s += __shfl_xor(s, 16, 64);
      s += __shfl_xor(s, 32, 64);
      if (lhi == 0) atomicAdd(&km[(b_ * 16 + (gc >> 6)) * 64 + (gc & 63)], s);
    }
  } else {
    // V: transpose 128(kv) x 128(ch) tile through LDS, then fragment-ordered stores.
    __syncthreads();
    unsigned* tb = (unsigned*)&sAB[0][0][0];       // 128 rows x 64 u32 = 32 KB
#pragma unroll
    for (int n = 0; n < 4; ++n) {
      const int gcL = wn * 64 + n * 16 + l15;      // local ch 0..127
      const float bb = bv[col0 + gcL];
#pragma unroll
      for (int m = 0; m < 4; ++m) {
#pragma unroll
        for (int k = 0; k < 2; ++k) {
          const int grPair = wm * 32 + m * 8 + lhi * 2 + k;   // kv pair 0..63
          const int W = (grPair & 3) | ((((grPair >> 2) ^ gcL) & 15) << 2);
          tb[gcL * 64 + W] = pkbf(acc[m][n][2 * k] + bb, acc[m][n][2 * k + 1] + bb);
        }
      }
    }
    __syncthreads();
    const int b_ = row0 >> 11;
#pragma unroll
    for (int it = 0; it < 8; ++it) {
      const int c = it * 256 + tid;                // 0..2047
      const int gcL = (c & 63) + ((c >> 10) << 6); // d-inner for dense frag stores
      const int u = (c >> 6) & 15;                 // kv-8-group
      const int W4 = (u ^ gcL) & 15;
      u32x4 o = *(const u32x4*)(tb + gcL * 64 + W4 * 4);
      const int kv0 = (row0 & 2047) + u * 8;
      const int ch = col0 + gcL;
      const int hh2 = ch >> 6, d = ch & 63;
      const int t2 = kv0 >> 6, ks2 = (kv0 >> 4) & 3, h5v = (kv0 >> 3) & 1;
      const size_t off = ((size_t)(b_ * 16 + hh2) << 17) +
                         (size_t)(((t2 * 4 + ks2) * 2 + (d >> 5)) * 64 + h5v * 32 + (d & 31)) * 8;
      *(u32x4*)(VFout + off) = o;
    }
  }
}

// ---------- fused flash attention + pooled gate + blend (R13 measured-best) ----------
// 512 blocks (XCD-swizzled bh), 256 threads = 4 waves, 32 q-rows/wave.
// K LDS-staged dbuf (1 barrier/tile); V reg-direct from fragment-ordered VF.
__global__ __launch_bounds__(256, 2)
void attn_fused(const unsigned short* __restrict__ Q,    // (B*SQ,1024) bf16, 0.125*log2e scaled
                const unsigned short* __restrict__ Kb,   // (B*SV,1024) bf16 row-major
                const unsigned short* __restrict__ VF,   // frag-ordered V^T
                const float* __restrict__ addm_g,        // (B,SV) 0/-1e30
                const float* __restrict__ km,            // (B,H,64)
                const float* __restrict__ counts,        // (B)
                const float* __restrict__ gain,          // (H)
                const float* __restrict__ gbias,         // (H)
                const float* __restrict__ pq,            // (B*SQ,1280) f32
                float* __restrict__ out) {               // (B*SQ,1280) f32
  __shared__ __align__(16) char smem[32768];
  unsigned short* sK = (unsigned short*)smem;            // [2][64*64] 16 KB
  float* saddm = (float*)(smem + 16384);                 // [2048] 8 KB
  float* sOT = (float*)smem;                             // epilogue overlay (32 KB)

  const int tid = threadIdx.x, lane = tid & 63, w = tid >> 6;
  const int l31 = lane & 31, h5 = lane >> 5;
  const int f = blockIdx.x;
  const int qt = (f >> 3) & 15;
  const int bh = (f & 7) + 8 * (f >> 7);
  const int b = bh >> 4, hh = bh & 15;
  const int q0 = qt * 128;

  // stage additive mask (2048 f32)
  GLOAD_LDS16(addm_g + b * 2048 + tid * 4, (char*)saddm + tid * 16);
  GLOAD_LDS16(addm_g + b * 2048 + 1024 + tid * 4, (char*)saddm + 4096 + tid * 16);

  // Q fragments (B-operand): lane l31 = q col, k = ks*16 + h5*8 + j
  bf16x8 qf[4];
  {
    const unsigned short* qp = Q + (size_t)(b * 2048 + q0 + w * 32 + l31) * 1024 + hh * 64 + h5 * 8;
#pragma unroll
    for (int ks = 0; ks < 4; ++ks) qf[ks] = *(const bf16x8*)(qp + ks * 16);
  }

  // pooled = km . q (log2-scaled; corrected by ln2 in the gate)
  float pl_s = 0.f;
  {
    const float* kmp = km + (b * 16 + hh) * 64 + h5 * 8;
#pragma unroll
    for (int ks = 0; ks < 4; ++ks) {
      f32x4 ka = *(const f32x4*)(kmp + ks * 16);
      f32x4 kb4 = *(const f32x4*)(kmp + ks * 16 + 4);
#pragma unroll
      for (int j = 0; j < 4; ++j)
        pl_s += (float)qf[ks][j] * ka[j] + (float)qf[ks][j + 4] * kb4[j];
    }
    float ta = pl_s, tb = pl_s;
    asm("v_permlane32_swap_b32 %0, %1" : "+v"(ta), "+v"(tb));
    pl_s = ta + tb;
  }

  const unsigned short* Kbase = Kb + (size_t)(b * 2048) * 1024 + hh * 64;
  const unsigned short* VFb = VF + ((size_t)bh << 17) + lane * 8;

  f32x16 o0, o1, l_vec;
#pragma unroll
  for (int r = 0; r < 16; ++r) { o0[r] = 0.f; o1[r] = 0.f; l_vec[r] = 0.f; }
  float m_ = -1e30f;

  auto stageK = [&](int buf, int kv) {
#pragma unroll
    for (int i = 0; i < 2; ++i) {
      const int c = i * 256 + tid;                       // 0..511
      const int r = c >> 3, sl = (c & 7) ^ (r & 7);
      GLOAD_LDS16(Kbase + (size_t)(kv + r) * 1024 + sl * 8, (char*)sK + buf * 8192 + c * 16);
    }
  };

  bf16x8 vf[8];
  auto ldV = [&](int t) {
    const unsigned short* p = VFb + (size_t)t * 4096;
#pragma unroll
    for (int i = 0; i < 8; ++i) vf[i] = *(const bf16x8*)(p + i * 512);
  };

  stageK(0, 0);
  __syncthreads();
  int cur = 0;

  for (int t = 0; t < 32; ++t) {
    if (t < 31) stageK(cur ^ 1, (t + 1) * 64);
    ldV(t);                                              // in flight under QK+softmax
    const char* sKc = (const char*)sK + cur * 8192;

    // S^T init = additive mask rows (C-initializer; broadcast LDS reads)
    f32x16 s0, s1;
#pragma unroll
    for (int g = 0; g < 4; ++g) {
      f32x4 a0 = *(const f32x4*)(saddm + t * 64 + g * 8 + h5 * 4);
      f32x4 a1 = *(const f32x4*)(saddm + t * 64 + 32 + g * 8 + h5 * 4);
#pragma unroll
      for (int j = 0; j < 4; ++j) { s0[g * 4 + j] = a0[j]; s1[g * 4 + j] = a1[j]; }
    }

    // S^T += K . Q (rows kv, cols q=lane)
#pragma unroll
    for (int ks = 0; ks < 4; ++ks) {
      const int sl = (((ks * 2 + h5) ^ (l31 & 7)) * 16);
      bf16x8 k0 = *(const bf16x8*)(sKc + l31 * 128 + sl);
      bf16x8 k1 = *(const bf16x8*)(sKc + (32 + l31) * 128 + sl);
      s0 = __builtin_amdgcn_mfma_f32_32x32x16_bf16(k0, qf[ks], s0, 0, 0, 0);
      s1 = __builtin_amdgcn_mfma_f32_32x32x16_bf16(k1, qf[ks], s1, 0, 0, 0);
    }

    // wave max (log2 domain), defer-max THR=11 (~8 nats)
    f32x16 mx;
#pragma unroll
    for (int r = 0; r < 16; ++r) mx[r] = fmaxf(s0[r], s1[r]);
    float t8[8];
#pragma unroll
    for (int r = 0; r < 8; ++r) t8[r] = fmaxf(mx[r], mx[r + 8]);
    float tp = fmaxf(fmaxf(fmaxf(t8[0], t8[1]), fmaxf(t8[2], t8[3])),
                     fmaxf(fmaxf(t8[4], t8[5]), fmaxf(t8[6], t8[7])));
    {
      float ta = tp, tb = tp;
      asm("v_permlane32_swap_b32 %0, %1" : "+v"(ta), "+v"(tb));
      tp = fmaxf(ta, tb);
    }
    if (__any(tp > m_ + 11.0f)) {
      const float mnew = fmaxf(m_, tp);
      const float corr = EXP2(m_ - mnew);
      m_ = mnew;
      l_vec *= corr; o0 *= corr; o1 *= corr;
    }

    // P = 2^(S - m)
    f32x16 p0, p1;
#pragma unroll
    for (int r = 0; r < 16; ++r) p0[r] = EXP2(s0[r] - m_);
#pragma unroll
    for (int r = 0; r < 16; ++r) p1[r] = EXP2(s1[r] - m_);
    l_vec += p0; l_vec += p1;

    // P^T B-fragments in-register: cvt_pk + permlane32_swap
    bf16x8 pfs[4];
    {
      unsigned x0 = pkbf(p0[0], p0[1]), y0 = pkbf(p0[2], p0[3]);
      unsigned z0 = pkbf(p0[4], p0[5]), w0 = pkbf(p0[6], p0[7]);
      asm("v_permlane32_swap_b32 %0, %1" : "+v"(x0), "+v"(z0));
      asm("v_permlane32_swap_b32 %0, %1" : "+v"(y0), "+v"(w0));
      u32x4 f0 = {x0, y0, z0, w0};
      pfs[0] = __builtin_bit_cast(bf16x8, f0);
      unsigned x1 = pkbf(p0[8], p0[9]), y1 = pkbf(p0[10], p0[11]);
      unsigned z1 = pkbf(p0[12], p0[13]), w1 = pkbf(p0[14], p0[15]);
      asm("v_permlane32_swap_b32 %0, %1" : "+v"(x1), "+v"(z1));
      asm("v_permlane32_swap_b32 %0, %1" : "+v"(y1), "+v"(w1));
      u32x4 f1 = {x1, y1, z1, w1};
      pfs[1] = __builtin_bit_cast(bf16x8, f1);
      unsigned x2 = pkbf(p1[0], p1[1]), y2 = pkbf(p1[2], p1[3]);
      unsigned z2 = pkbf(p1[4], p1[5]), w2 = pkbf(p1[6], p1[7]);
      asm("v_permlane32_swap_b32 %0, %1" : "+v"(x2), "+v"(z2));
      asm("v_permlane32_swap_b32 %0, %1" : "+v"(y2), "+v"(w2));
      u32x4 f2 = {x2, y2, z2, w2};
      pfs[2] = __builtin_bit_cast(bf16x8, f2);
      unsigned x3 = pkbf(p1[8], p1[9]), y3 = pkbf(p1[10], p1[11]);
      unsigned z3 = pkbf(p1[12], p1[13]), w3 = pkbf(p1[14], p1[15]);
      asm("v_permlane32_swap_b32 %0, %1" : "+v"(x3), "+v"(z3));
      asm("v_permlane32_swap_b32 %0, %1" : "+v"(y3), "+v"(w3));
      u32x4 f3 = {x3, y3, z3, w3};
      pfs[3] = __builtin_bit_cast(bf16x8, f3);
    }

    // O^T += V^T . P^T  (V from registers, frag-ordered global)
#pragma unroll
    for (int ks = 0; ks < 4; ++ks) {
      o0 = __builtin_amdgcn_mfma_f32_32x32x16_bf16(vf[ks * 2], pfs[ks], o0, 0, 0, 0);
      o1 = __builtin_amdgcn_mfma_f32_32x32x16_bf16(vf[ks * 2 + 1], pfs[ks], o1, 0, 0, 0);
    }
    __syncthreads();
    cur ^= 1;
  }

  // final reductions (horizontal + cross-half)
  float l_s;
  {
    float a[8];
#pragma unroll
    for (int r = 0; r < 8; ++r) a[r] = l_vec[r] + l_vec[r + 8];
    l_s = ((a[0] + a[1]) + (a[2] + a[3])) + ((a[4] + a[5]) + (a[6] + a[7]));
    float ta = l_s, tb = l_s;
    asm("v_permlane32_swap_b32 %0, %1" : "+v"(ta), "+v"(tb));
    l_s = ta + tb;
  }
  const float po = pl_s * 0.6931471805599453f / counts[b];
  const float wgv = 1.f / (1.f + __expf(-(po * gain[hh] + gbias[hh])));
  const float invl = 1.f / l_s;

  // transpose O^T -> O through wave-private swizzled LDS overlay
  __syncthreads();
  float* myOT = sOT + w * 2048;
#pragma unroll
  for (int r = 0; r < 16; ++r) {
    const int d0 = (r & 3) + 8 * (r >> 2) + 4 * h5;
    myOT[d0 * 32 + (l31 ^ (d0 & 31))] = o0[r] * invl;
    const int d1 = d0 + 32;
    myOT[d1 * 32 + (l31 ^ (d1 & 31))] = o1[r] * invl;
  }
  __syncthreads();
  const size_t rowbase = (size_t)(b * 2048 + q0 + w * 32) * 1280 + hh * 64 + lane;
  const float* pqrow = pq + rowbase;
  float* outrow = out + rowbase;
#pragma unroll 4
  for (int i = 0; i < 32; ++i) {
    const float hval = myOT[lane * 32 + (i ^ (lane & 31))];
    const float wgrow = __shfl(wgv, i, 64);
    const float pv = pqrow[(size_t)i * 1280];
    outrow[(size_t)i * 1280] = fmaf(hval - pv, wgrow, pv);
  }
}

extern "C" void kernel_launch(void* const* d_in, const int* in_sizes, int n_in,
                              void* d_out, int out_size, void* d_ws, size_t ws_size,
                              hipStream_t stream) {
  const float* pre_vk = (const float*)d_in[0];
  const float* pre_q  = (const float*)d_in[1];
  const float* vmask  = (const float*)d_in[2];
  const float* vcnt   = (const float*)d_in[3];
  const float* Wq = (const float*)d_in[4];
  const float* bq = (const float*)d_in[5];
  const float* Wk = (const float*)d_in[6];
  const float* bk = (const float*)d_in[7];
  const float* Wv = (const float*)d_in[8];
  const float* bv = (const float*)d_in[9];
  const float* gain  = (const float*)d_in[10];
  const float* gbias = (const float*)d_in[11];
  float* out = (float*)d_out;

  char* ws = (char*)d_ws;
  unsigned short* pq_bf = (unsigned short*)(ws);              // 4096x1280 bf16
  unsigned short* pv_bf = (unsigned short*)(ws + 10485760);   // 4096x1024
  unsigned short* WqT   = (unsigned short*)(ws + 18874368);   // 1024x1280
  unsigned short* WkT   = (unsigned short*)(ws + 21495808);   // 1024x1024
  unsigned short* WvT   = (unsigned short*)(ws + 23592960);   // 1024x1024
  unsigned short* Qb    = (unsigned short*)(ws + 25690112);   // 4096x1024 (0.125*log2e scaled)
  unsigned short* Kbb   = (unsigned short*)(ws + 34078720);   // 4096x1024 row-major K
  unsigned short* VFb   = (unsigned short*)(ws + 42467328);   // frag-ordered V^T, 8 MB
  float*          kmb   = (float*)(ws + 50855936);            // (2,16,64)
  float*          addm  = (float*)(ws + 50864128);            // (2,2048) f32

  prep_all<<<13072, 256, 0, stream>>>(pre_q, pre_vk, Wq, Wk, Wv, vmask,
                                      pq_bf, pv_bf, WqT, WkT, WvT, addm, kmb, out);
  gemm_all<<<768, 256, 0, stream>>>(pq_bf, pv_bf, WqT, WkT, WvT, bq, bk, bv, vmask,
                                    Qb, Kbb, VFb, kmb);
  attn_fused<<<512, 256, 0, stream>>>(Qb, Kbb, VFb, addm, kmb, vcnt, gain, gbias, pre_q, out);
}